// Round 1
// baseline (5130.875 us; speedup 1.0000x reference)
//
#include <hip/hip_runtime.h>
#include <math.h>

// GEMM: out[r][c] = sum_k X[r][k] * W[k][c]  (+ b0+b1+b2 if non-null)
// K fixed at 128. Tile 64x64, 256 threads, 4x4 micro-tile.
template<int M>
__global__ __launch_bounds__(256)
void gemm_k128(const float* __restrict__ X, const float* __restrict__ W,
               const float* __restrict__ b0, const float* __restrict__ b1,
               const float* __restrict__ b2, float* __restrict__ out, int nrows)
{
    constexpr int BM = 64, BN = 64, K = 128;
    constexpr int XPAD = 132;                 // 132 floats: 16B-aligned rows, conflict-light
    __shared__ float xs[BM][XPAD];
    __shared__ float ws[K][BN];
    const int tid  = threadIdx.x;
    const int row0 = blockIdx.x * BM;
    const int col0 = blockIdx.y * BN;

    // X tile: 64 rows x 128 k = 2048 float4, 8 per thread (coalesced)
    #pragma unroll
    for (int t = 0; t < 8; ++t) {
        int idx = tid + t * 256;              // 0..2047
        int row = idx >> 5;                   // 32 f4 per row
        int kq  = idx & 31;
        int gr  = row0 + row;
        float4 v = make_float4(0.f, 0.f, 0.f, 0.f);
        if (gr < nrows) v = *(const float4*)(X + (size_t)gr * K + kq * 4);
        *(float4*)&xs[row][kq * 4] = v;
    }
    // W tile: 128 k x 64 cols = 2048 float4, 8 per thread
    #pragma unroll
    for (int t = 0; t < 8; ++t) {
        int idx = tid + t * 256;
        int kr  = idx >> 4;                   // 16 f4 per k-row
        int cq  = idx & 15;
        int c   = col0 + cq * 4;
        float4 v = make_float4(0.f, 0.f, 0.f, 0.f);
        if (c + 3 < M) v = *(const float4*)(W + (size_t)kr * M + c);
        *(float4*)&ws[kr][cq * 4] = v;
    }
    __syncthreads();

    const int tx = tid & 15, ty = tid >> 4;   // cols tx*4.., rows ty*4..
    const int tx4 = tx * 4, ty4 = ty * 4;
    float acc[4][4] = {};
    #pragma unroll 4
    for (int k = 0; k < K; ++k) {
        float a[4];
        #pragma unroll
        for (int i = 0; i < 4; ++i) a[i] = xs[ty4 + i][k];
        float4 bv = *(const float4*)&ws[k][tx4];
        float b[4] = {bv.x, bv.y, bv.z, bv.w};
        #pragma unroll
        for (int i = 0; i < 4; ++i)
            #pragma unroll
            for (int j = 0; j < 4; ++j)
                acc[i][j] = fmaf(a[i], b[j], acc[i][j]);
    }

    float bias[4];
    #pragma unroll
    for (int j = 0; j < 4; ++j) {
        int c = col0 + tx4 + j;
        float s = 0.f;
        if (c < M) {
            if (b0) s += b0[c];
            if (b1) s += b1[c];
            if (b2) s += b2[c];
        }
        bias[j] = s;
    }
    #pragma unroll
    for (int i = 0; i < 4; ++i) {
        int r = row0 + ty4 + i;
        if (r >= nrows) continue;
        #pragma unroll
        for (int j = 0; j < 4; ++j) {
            int c = col0 + tx4 + j;
            if (c < M) out[(size_t)r * M + c] = acc[i][j] + bias[j];
        }
    }
}

// out[dst[e]] += ew[e] * h[src[e]], feature width 128. 32 lanes x float4 per edge.
__global__ __launch_bounds__(256)
void scatter128(const float* __restrict__ h, const int* __restrict__ ei,
                const float* __restrict__ ew, float* __restrict__ out, int E)
{
    int e = blockIdx.x * 8 + (threadIdx.x >> 5);
    if (e >= E) return;
    int lane = threadIdx.x & 31;
    int s = ei[e];
    int d = ei[E + e];
    float w = ew[e];
    float4 v = *(const float4*)(h + (size_t)s * 128 + lane * 4);
    float* o = out + (size_t)d * 128 + lane * 4;
    atomicAdd(o + 0, w * v.x);
    atomicAdd(o + 1, w * v.y);
    atomicAdd(o + 2, w * v.z);
    atomicAdd(o + 3, w * v.w);
}

// Same at width 40. 16 threads per edge, lanes 0..9 carry float4.
__global__ __launch_bounds__(256)
void scatter40(const float* __restrict__ h, const int* __restrict__ ei,
               const float* __restrict__ ew, float* __restrict__ out, int E)
{
    int e = blockIdx.x * 16 + (threadIdx.x >> 4);
    if (e >= E) return;
    int lane = threadIdx.x & 15;
    if (lane >= 10) return;
    int s = ei[e];
    int d = ei[E + e];
    float w = ew[e];
    float4 v = *(const float4*)(h + (size_t)s * 40 + lane * 4);
    float* o = out + (size_t)d * 40 + lane * 4;
    atomicAdd(o + 0, w * v.x);
    atomicAdd(o + 1, w * v.y);
    atomicAdd(o + 2, w * v.z);
    atomicAdd(o + 3, w * v.w);
}

// log_softmax over 40 columns; one wave (64 lanes) per row.
__global__ __launch_bounds__(256)
void logsoftmax40(const float* __restrict__ in, float* __restrict__ out, int nrows)
{
    int wave = threadIdx.x >> 6;
    int lane = threadIdx.x & 63;
    int r = blockIdx.x * 4 + wave;
    if (r >= nrows) return;
    float v = (lane < 40) ? in[(size_t)r * 40 + lane] : -INFINITY;
    float m = v;
    #pragma unroll
    for (int off = 32; off; off >>= 1) m = fmaxf(m, __shfl_xor(m, off, 64));
    float e = (lane < 40) ? expf(v - m) : 0.f;
    float s = e;
    #pragma unroll
    for (int off = 32; off; off >>= 1) s += __shfl_xor(s, off, 64);
    if (lane < 40) out[(size_t)r * 40 + lane] = v - m - logf(s);
}

extern "C" void kernel_launch(void* const* d_in, const int* in_sizes, int n_in,
                              void* d_out, int out_size, void* d_ws, size_t ws_size,
                              hipStream_t stream)
{
    const float* x    = (const float*)d_in[0];
    const int*   ei1  = (const int*)  d_in[1];
    const float* ew1  = (const float*)d_in[2];
    const int*   ei2  = (const int*)  d_in[3];
    const float* ew2  = (const float*)d_in[4];

    const float* W_ln1 = (const float*)d_in[5];   const float* b_ln1 = (const float*)d_in[6];
    const float* W_c11 = (const float*)d_in[7];   const float* b_c11 = (const float*)d_in[8];
    const float* W_c21 = (const float*)d_in[9];   const float* b_c21 = (const float*)d_in[10];
    const float* W_ln2 = (const float*)d_in[11];  const float* b_ln2 = (const float*)d_in[12];
    const float* W_c12 = (const float*)d_in[13];  const float* b_c12 = (const float*)d_in[14];
    const float* W_c22 = (const float*)d_in[15];  const float* b_c22 = (const float*)d_in[16];
    const float* W_ln3 = (const float*)d_in[17];  const float* b_ln3 = (const float*)d_in[18];
    const float* W_c13 = (const float*)d_in[19];  const float* b_c13 = (const float*)d_in[20];
    const float* W_c23 = (const float*)d_in[21];  const float* b_c23 = (const float*)d_in[22];

    const int N = in_sizes[0] / 128;   // 50000
    const int E = in_sizes[2];         // 600000

    float* xA = (float*)d_ws;                  // N x 128 (also final N x 40)
    float* xB = xA + (size_t)N * 128;          // N x 128
    float* hc = xB + (size_t)N * 128;          // N x 128 scratch for conv GEMM outputs

    dim3 blk(256);
    dim3 g128((N + 63) / 64, 2);
    dim3 g40((N + 63) / 64, 1);
    dim3 gs128((E + 7) / 8);
    dim3 gs40((E + 15) / 16);
    dim3 gls((N + 3) / 4);

    // ---- Block 1: x -> xA ----
    gemm_k128<128><<<g128, blk, 0, stream>>>(x, W_ln1, b_ln1, b_c11, b_c21, xA, N);
    gemm_k128<128><<<g128, blk, 0, stream>>>(x, W_c11, nullptr, nullptr, nullptr, hc, N);
    scatter128<<<gs128, blk, 0, stream>>>(hc, ei1, ew1, xA, E);
    gemm_k128<128><<<g128, blk, 0, stream>>>(x, W_c21, nullptr, nullptr, nullptr, hc, N);
    scatter128<<<gs128, blk, 0, stream>>>(hc, ei2, ew2, xA, E);

    // ---- Block 2: xA -> xB ----
    gemm_k128<128><<<g128, blk, 0, stream>>>(xA, W_ln2, b_ln2, b_c12, b_c22, xB, N);
    gemm_k128<128><<<g128, blk, 0, stream>>>(xA, W_c12, nullptr, nullptr, nullptr, hc, N);
    scatter128<<<gs128, blk, 0, stream>>>(hc, ei1, ew1, xB, E);
    gemm_k128<128><<<g128, blk, 0, stream>>>(xA, W_c22, nullptr, nullptr, nullptr, hc, N);
    scatter128<<<gs128, blk, 0, stream>>>(hc, ei2, ew2, xB, E);

    // ---- Block 3: xB -> xA (width 40) ----
    gemm_k128<40><<<g40, blk, 0, stream>>>(xB, W_ln3, b_ln3, b_c13, b_c23, xA, N);
    gemm_k128<40><<<g40, blk, 0, stream>>>(xB, W_c13, nullptr, nullptr, nullptr, hc, N);
    scatter40<<<gs40, blk, 0, stream>>>(hc, ei1, ew1, xA, E);
    gemm_k128<40><<<g40, blk, 0, stream>>>(xB, W_c23, nullptr, nullptr, nullptr, hc, N);
    scatter40<<<gs40, blk, 0, stream>>>(hc, ei2, ew2, xA, E);

    // ---- log_softmax -> d_out ----
    logsoftmax40<<<gls, blk, 0, stream>>>(xA, (float*)d_out, N);
}

// Round 2
// 800.388 us; speedup vs baseline: 6.4105x; 6.4105x over previous
//
#include <hip/hip_runtime.h>
#include <math.h>

// ---------------- GEMM: out[r][c] = sum_k X[r][k]*W[k][c] (+ b0+b1+b2) ----------------
template<int M>
__global__ __launch_bounds__(256)
void gemm_k128(const float* __restrict__ X, const float* __restrict__ W,
               const float* __restrict__ b0, const float* __restrict__ b1,
               const float* __restrict__ b2, float* __restrict__ out, int nrows)
{
    constexpr int BM = 64, BN = 64, K = 128;
    constexpr int XPAD = 132;
    __shared__ float xs[BM][XPAD];
    __shared__ float ws[K][BN];
    const int tid  = threadIdx.x;
    const int row0 = blockIdx.x * BM;
    const int col0 = blockIdx.y * BN;

    #pragma unroll
    for (int t = 0; t < 8; ++t) {
        int idx = tid + t * 256;
        int row = idx >> 5;
        int kq  = idx & 31;
        int gr  = row0 + row;
        float4 v = make_float4(0.f, 0.f, 0.f, 0.f);
        if (gr < nrows) v = *(const float4*)(X + (size_t)gr * K + kq * 4);
        *(float4*)&xs[row][kq * 4] = v;
    }
    #pragma unroll
    for (int t = 0; t < 8; ++t) {
        int idx = tid + t * 256;
        int kr  = idx >> 4;
        int cq  = idx & 15;
        int c   = col0 + cq * 4;
        float4 v = make_float4(0.f, 0.f, 0.f, 0.f);
        if (c + 3 < M) v = *(const float4*)(W + (size_t)kr * M + c);
        *(float4*)&ws[kr][cq * 4] = v;
    }
    __syncthreads();

    const int tx = tid & 15, ty = tid >> 4;
    const int tx4 = tx * 4, ty4 = ty * 4;
    float acc[4][4] = {};
    #pragma unroll 4
    for (int k = 0; k < K; ++k) {
        float a[4];
        #pragma unroll
        for (int i = 0; i < 4; ++i) a[i] = xs[ty4 + i][k];
        float4 bv = *(const float4*)&ws[k][tx4];
        float b[4] = {bv.x, bv.y, bv.z, bv.w};
        #pragma unroll
        for (int i = 0; i < 4; ++i)
            #pragma unroll
            for (int j = 0; j < 4; ++j)
                acc[i][j] = fmaf(a[i], b[j], acc[i][j]);
    }

    float bias[4];
    #pragma unroll
    for (int j = 0; j < 4; ++j) {
        int c = col0 + tx4 + j;
        float s = 0.f;
        if (c < M) {
            if (b0) s += b0[c];
            if (b1) s += b1[c];
            if (b2) s += b2[c];
        }
        bias[j] = s;
    }
    #pragma unroll
    for (int i = 0; i < 4; ++i) {
        int r = row0 + ty4 + i;
        if (r >= nrows) continue;
        #pragma unroll
        for (int j = 0; j < 4; ++j) {
            int c = col0 + tx4 + j;
            if (c < M) out[(size_t)r * M + c] = acc[i][j] + bias[j];
        }
    }
}

// ---------------- CSR build ----------------
__global__ void zero_i32(int* __restrict__ p, int n)
{
    int i = blockIdx.x * blockDim.x + threadIdx.x;
    if (i < n) p[i] = 0;
}

__global__ void hist_dst(const int* __restrict__ ei, int E, int* __restrict__ cnt)
{
    int e = blockIdx.x * blockDim.x + threadIdx.x;
    if (e < E) atomicAdd(&cnt[ei[E + e]], 1);
}

// 3-phase exclusive scan over n entries (reads cnt[i] for i<ncnt, else 0)
__global__ void scan_phase1(const int* __restrict__ cnt, int ncnt, int* __restrict__ bsums, int n)
{
    __shared__ int s[256];
    int tid = threadIdx.x;
    int i = blockIdx.x * 256 + tid;
    int v = (i < n && i < ncnt) ? cnt[i] : 0;
    s[tid] = v; __syncthreads();
    for (int off = 128; off; off >>= 1) {
        if (tid < off) s[tid] += s[tid + off];
        __syncthreads();
    }
    if (tid == 0) bsums[blockIdx.x] = s[0];
}

__global__ void scan_phase2(int* __restrict__ bsums, int nb)
{
    __shared__ int s[256];
    int tid = threadIdx.x;
    int v = (tid < nb) ? bsums[tid] : 0;
    s[tid] = v; __syncthreads();
    for (int off = 1; off < 256; off <<= 1) {
        int t = (tid >= off) ? s[tid - off] : 0;
        __syncthreads();
        s[tid] += t;
        __syncthreads();
    }
    if (tid < nb) bsums[tid] = s[tid] - v;   // exclusive
}

__global__ void scan_phase3(const int* __restrict__ cnt, int ncnt,
                            const int* __restrict__ bsums, int* __restrict__ row_ptr, int n)
{
    __shared__ int s[256];
    int tid = threadIdx.x;
    int i = blockIdx.x * 256 + tid;
    int v = (i < n && i < ncnt) ? cnt[i] : 0;
    s[tid] = v; __syncthreads();
    for (int off = 1; off < 256; off <<= 1) {
        int t = (tid >= off) ? s[tid - off] : 0;
        __syncthreads();
        s[tid] += t;
        __syncthreads();
    }
    if (i < n) row_ptr[i] = s[tid] - v + bsums[blockIdx.x];
}

__global__ void fill_eids(const int* __restrict__ ei, int E,
                          const int* __restrict__ row_ptr, int* __restrict__ cur,
                          int* __restrict__ eids)
{
    int e = blockIdx.x * blockDim.x + threadIdx.x;
    if (e >= E) return;
    int d = ei[E + e];
    int p = row_ptr[d] + atomicAdd(&cur[d], 1);
    eids[p] = e;
}

// per-row insertion sort of edge ids -> deterministic accumulation order
__global__ void sort_rows(const int* __restrict__ row_ptr, int* __restrict__ eids, int N)
{
    int r = blockIdx.x * blockDim.x + threadIdx.x;
    if (r >= N) return;
    int b = row_ptr[r], e = row_ptr[r + 1];
    for (int i = b + 1; i < e; ++i) {
        int v = eids[i];
        int j = i - 1;
        while (j >= b && eids[j] > v) { eids[j + 1] = eids[j]; --j; }
        eids[j + 1] = v;
    }
}

__global__ void permute_edges(const int* __restrict__ eids, const int* __restrict__ ei,
                              const float* __restrict__ ew, int E,
                              int* __restrict__ srcp, float* __restrict__ wp)
{
    int i = blockIdx.x * blockDim.x + threadIdx.x;
    if (i >= E) return;
    int e = eids[i];
    srcp[i] = ei[e];       // source node
    wp[i]   = ew[e];
}

// ---------------- gather: out[d] += sum_e w[e]*h[src[e]] ----------------
__global__ __launch_bounds__(256)
void gather_add128(const float* __restrict__ h, const int* __restrict__ row_ptr,
                   const int* __restrict__ srcp, const float* __restrict__ wp,
                   float* __restrict__ out, int N)
{
    int row = blockIdx.x * 8 + (threadIdx.x >> 5);
    if (row >= N) return;
    int lane = threadIdx.x & 31;
    int beg = row_ptr[row], end = row_ptr[row + 1];
    float4 a0 = make_float4(0.f,0.f,0.f,0.f);
    float4 a1 = make_float4(0.f,0.f,0.f,0.f);
    int i = beg;
    for (; i + 2 <= end; i += 2) {
        int   s0 = srcp[i],  s1 = srcp[i + 1];
        float w0 = wp[i],    w1 = wp[i + 1];
        float4 v0 = *(const float4*)(h + (size_t)s0 * 128 + lane * 4);
        float4 v1 = *(const float4*)(h + (size_t)s1 * 128 + lane * 4);
        a0.x = fmaf(w0, v0.x, a0.x); a0.y = fmaf(w0, v0.y, a0.y);
        a0.z = fmaf(w0, v0.z, a0.z); a0.w = fmaf(w0, v0.w, a0.w);
        a1.x = fmaf(w1, v1.x, a1.x); a1.y = fmaf(w1, v1.y, a1.y);
        a1.z = fmaf(w1, v1.z, a1.z); a1.w = fmaf(w1, v1.w, a1.w);
    }
    if (i < end) {
        int   s0 = srcp[i];
        float w0 = wp[i];
        float4 v0 = *(const float4*)(h + (size_t)s0 * 128 + lane * 4);
        a0.x = fmaf(w0, v0.x, a0.x); a0.y = fmaf(w0, v0.y, a0.y);
        a0.z = fmaf(w0, v0.z, a0.z); a0.w = fmaf(w0, v0.w, a0.w);
    }
    float* o = out + (size_t)row * 128 + lane * 4;
    float4 c = *(float4*)o;
    c.x += a0.x + a1.x; c.y += a0.y + a1.y;
    c.z += a0.z + a1.z; c.w += a0.w + a1.w;
    *(float4*)o = c;
}

__global__ __launch_bounds__(256)
void gather_add40(const float* __restrict__ h, const int* __restrict__ row_ptr,
                  const int* __restrict__ srcp, const float* __restrict__ wp,
                  float* __restrict__ out, int N)
{
    int row = blockIdx.x * 16 + (threadIdx.x >> 4);
    int lane = threadIdx.x & 15;
    if (row >= N || lane >= 10) return;
    int beg = row_ptr[row], end = row_ptr[row + 1];
    float4 a0 = make_float4(0.f,0.f,0.f,0.f);
    float4 a1 = make_float4(0.f,0.f,0.f,0.f);
    int i = beg;
    for (; i + 2 <= end; i += 2) {
        int   s0 = srcp[i],  s1 = srcp[i + 1];
        float w0 = wp[i],    w1 = wp[i + 1];
        float4 v0 = *(const float4*)(h + (size_t)s0 * 40 + lane * 4);
        float4 v1 = *(const float4*)(h + (size_t)s1 * 40 + lane * 4);
        a0.x = fmaf(w0, v0.x, a0.x); a0.y = fmaf(w0, v0.y, a0.y);
        a0.z = fmaf(w0, v0.z, a0.z); a0.w = fmaf(w0, v0.w, a0.w);
        a1.x = fmaf(w1, v1.x, a1.x); a1.y = fmaf(w1, v1.y, a1.y);
        a1.z = fmaf(w1, v1.z, a1.z); a1.w = fmaf(w1, v1.w, a1.w);
    }
    if (i < end) {
        int   s0 = srcp[i];
        float w0 = wp[i];
        float4 v0 = *(const float4*)(h + (size_t)s0 * 40 + lane * 4);
        a0.x = fmaf(w0, v0.x, a0.x); a0.y = fmaf(w0, v0.y, a0.y);
        a0.z = fmaf(w0, v0.z, a0.z); a0.w = fmaf(w0, v0.w, a0.w);
    }
    float* o = out + (size_t)row * 40 + lane * 4;
    float4 c = *(float4*)o;
    c.x += a0.x + a1.x; c.y += a0.y + a1.y;
    c.z += a0.z + a1.z; c.w += a0.w + a1.w;
    *(float4*)o = c;
}

// ---------------- log_softmax over 40 cols, one wave per row ----------------
__global__ __launch_bounds__(256)
void logsoftmax40(const float* __restrict__ in, float* __restrict__ out, int nrows)
{
    int wave = threadIdx.x >> 6;
    int lane = threadIdx.x & 63;
    int r = blockIdx.x * 4 + wave;
    if (r >= nrows) return;
    float v = (lane < 40) ? in[(size_t)r * 40 + lane] : -INFINITY;
    float m = v;
    #pragma unroll
    for (int off = 32; off; off >>= 1) m = fmaxf(m, __shfl_xor(m, off, 64));
    float e = (lane < 40) ? expf(v - m) : 0.f;
    float s = e;
    #pragma unroll
    for (int off = 32; off; off >>= 1) s += __shfl_xor(s, off, 64);
    if (lane < 40) out[(size_t)r * 40 + lane] = v - m - logf(s);
}

// ---------------- launch ----------------
extern "C" void kernel_launch(void* const* d_in, const int* in_sizes, int n_in,
                              void* d_out, int out_size, void* d_ws, size_t ws_size,
                              hipStream_t stream)
{
    const float* x    = (const float*)d_in[0];
    const int*   ei1  = (const int*)  d_in[1];
    const float* ew1  = (const float*)d_in[2];
    const int*   ei2  = (const int*)  d_in[3];
    const float* ew2  = (const float*)d_in[4];

    const float* W_ln1 = (const float*)d_in[5];   const float* b_ln1 = (const float*)d_in[6];
    const float* W_c11 = (const float*)d_in[7];   const float* b_c11 = (const float*)d_in[8];
    const float* W_c21 = (const float*)d_in[9];   const float* b_c21 = (const float*)d_in[10];
    const float* W_ln2 = (const float*)d_in[11];  const float* b_ln2 = (const float*)d_in[12];
    const float* W_c12 = (const float*)d_in[13];  const float* b_c12 = (const float*)d_in[14];
    const float* W_c22 = (const float*)d_in[15];  const float* b_c22 = (const float*)d_in[16];
    const float* W_ln3 = (const float*)d_in[17];  const float* b_ln3 = (const float*)d_in[18];
    const float* W_c13 = (const float*)d_in[19];  const float* b_c13 = (const float*)d_in[20];
    const float* W_c23 = (const float*)d_in[21];  const float* b_c23 = (const float*)d_in[22];

    const int N = in_sizes[0] / 128;   // 50000
    const int E = in_sizes[2];         // 600000

    // ---- workspace layout (256B-aligned regions) ----
    auto align_up = [](size_t v) { return (v + 255) & ~(size_t)255; };
    char* base = (char*)d_ws;
    size_t off = 0;
    auto take = [&](size_t bytes) { char* p = base + off; off += align_up(bytes); return p; };

    float* xA = (float*)take((size_t)N * 128 * 4);
    float* xB = (float*)take((size_t)N * 128 * 4);
    float* hc = (float*)take((size_t)N * 128 * 4);

    int*   cnt[2];  int* row_ptr[2];  int* eids[2];  int* srcp[2];  float* wp[2];  int* bsums[2];
    for (int s = 0; s < 2; ++s) {
        cnt[s]     = (int*)  take((size_t)N * 4);
        row_ptr[s] = (int*)  take((size_t)(N + 1) * 4);
        eids[s]    = (int*)  take((size_t)E * 4);
        srcp[s]    = (int*)  take((size_t)E * 4);
        wp[s]      = (float*)take((size_t)E * 4);
        bsums[s]   = (int*)  take(256 * 4);
    }

    dim3 blk(256);
    const int gN    = (N + 255) / 256;          // 196
    const int gN1   = (N + 1 + 255) / 256;      // scan over N+1
    const int gE    = (E + 255) / 256;          // 2344
    dim3 g128((N + 63) / 64, 2);
    dim3 g40((N + 63) / 64, 1);
    dim3 gg128((N + 7) / 8);
    dim3 gg40((N + 15) / 16);
    dim3 gls((N + 3) / 4);

    // ---- build CSR for both edge sets ----
    const int* eis[2] = { ei1, ei2 };
    const float* ews[2] = { ew1, ew2 };
    for (int s = 0; s < 2; ++s) {
        zero_i32<<<gN, blk, 0, stream>>>(cnt[s], N);
        hist_dst<<<gE, blk, 0, stream>>>(eis[s], E, cnt[s]);
        scan_phase1<<<gN1, blk, 0, stream>>>(cnt[s], N, bsums[s], N + 1);
        scan_phase2<<<1, blk, 0, stream>>>(bsums[s], gN1);
        scan_phase3<<<gN1, blk, 0, stream>>>(cnt[s], N, bsums[s], row_ptr[s], N + 1);
        zero_i32<<<gN, blk, 0, stream>>>(cnt[s], N);          // reuse as fill cursor
        fill_eids<<<gE, blk, 0, stream>>>(eis[s], E, row_ptr[s], cnt[s], eids[s]);
        sort_rows<<<gN, blk, 0, stream>>>(row_ptr[s], eids[s], N);
        permute_edges<<<gE, blk, 0, stream>>>(eids[s], eis[s], ews[s], E, srcp[s], wp[s]);
    }

    // ---- Block 1: x -> xA ----
    gemm_k128<128><<<g128, blk, 0, stream>>>(x, W_ln1, b_ln1, b_c11, b_c21, xA, N);
    gemm_k128<128><<<g128, blk, 0, stream>>>(x, W_c11, nullptr, nullptr, nullptr, hc, N);
    gather_add128<<<gg128, blk, 0, stream>>>(hc, row_ptr[0], srcp[0], wp[0], xA, N);
    gemm_k128<128><<<g128, blk, 0, stream>>>(x, W_c21, nullptr, nullptr, nullptr, hc, N);
    gather_add128<<<gg128, blk, 0, stream>>>(hc, row_ptr[1], srcp[1], wp[1], xA, N);

    // ---- Block 2: xA -> xB ----
    gemm_k128<128><<<g128, blk, 0, stream>>>(xA, W_ln2, b_ln2, b_c12, b_c22, xB, N);
    gemm_k128<128><<<g128, blk, 0, stream>>>(xA, W_c12, nullptr, nullptr, nullptr, hc, N);
    gather_add128<<<gg128, blk, 0, stream>>>(hc, row_ptr[0], srcp[0], wp[0], xB, N);
    gemm_k128<128><<<g128, blk, 0, stream>>>(xA, W_c22, nullptr, nullptr, nullptr, hc, N);
    gather_add128<<<gg128, blk, 0, stream>>>(hc, row_ptr[1], srcp[1], wp[1], xB, N);

    // ---- Block 3: xB -> xA (width 40) ----
    gemm_k128<40><<<g40, blk, 0, stream>>>(xB, W_ln3, b_ln3, b_c13, b_c23, xA, N);
    gemm_k128<40><<<g40, blk, 0, stream>>>(xB, W_c13, nullptr, nullptr, nullptr, hc, N);
    gather_add40<<<gg40, blk, 0, stream>>>(hc, row_ptr[0], srcp[0], wp[0], xA, N);
    gemm_k128<40><<<g40, blk, 0, stream>>>(xB, W_c23, nullptr, nullptr, nullptr, hc, N);
    gather_add40<<<gg40, blk, 0, stream>>>(hc, row_ptr[1], srcp[1], wp[1], xA, N);

    // ---- log_softmax -> d_out ----
    logsoftmax40<<<gls, blk, 0, stream>>>(xA, (float*)d_out, N);
}

// Round 3
// 578.256 us; speedup vs baseline: 8.8730x; 1.3841x over previous
//
#include <hip/hip_runtime.h>
#include <math.h>

typedef _Float16 f16x8 __attribute__((ext_vector_type(8)));
typedef _Float16 f16x4 __attribute__((ext_vector_type(4)));
typedef float    f32x4 __attribute__((ext_vector_type(4)));

// ---------------- W preprocess: f32 [k][col] -> f16 hi/lo, transposed [col][k] ----------------
// dst layout: [hi: MPAD*128][lo: MPAD*128], row stride 128 (k-dim), zero-filled for col >= M
__global__ void wsplit(const float* __restrict__ W, _Float16* __restrict__ dst,
                       int M, int MPAD)
{
    int idx = blockIdx.x * 256 + threadIdx.x;
    if (idx >= MPAD * 128) return;
    int col = idx >> 7, k = idx & 127;
    float v = (col < M) ? W[(size_t)k * M + col] : 0.f;
    _Float16 h = (_Float16)v;
    _Float16 l = (_Float16)(v - (float)h);
    dst[(size_t)col * 128 + k] = h;
    dst[(size_t)MPAD * 128 + (size_t)col * 128 + k] = l;
}

// ---------------- fused 3-branch GEMM, split-f16 MFMA ----------------
// out = X[64xK=128] @ W[128xM] for 3 weight matrices; branch0 adds (b0+b1+b2).
// Wt: per branch [hi MPAD*128][lo MPAD*128], f16, layout [col][k].
template<int MPAD>
__global__ __launch_bounds__(256)
void gemm3(const float* __restrict__ X, const _Float16* __restrict__ Wt,
           const float* __restrict__ b0, const float* __restrict__ b1,
           const float* __restrict__ b2,
           float* __restrict__ out0, float* __restrict__ out1, float* __restrict__ out2,
           int M, int nrows)
{
    constexpr int KP = 136;                       // 128 + 8 f16 pad (272B row, 16B-aligned)
    __shared__ _Float16 xh[64][KP], xl[64][KP];
    __shared__ _Float16 wh[64][KP], wl[64][KP];

    const int tid  = threadIdx.x;
    const int row0 = blockIdx.x * 64;
    const int col0 = blockIdx.y * 64;

    // ---- stage X tile (64 rows x 128 k), split f32 -> f16 hi/lo ----
    #pragma unroll
    for (int i = 0; i < 8; ++i) {
        int idx = tid + i * 256;                  // 0..2047
        int row = idx >> 5;
        int k   = (idx & 31) * 4;
        int gr  = row0 + row;
        float4 v = make_float4(0.f, 0.f, 0.f, 0.f);
        if (gr < nrows) v = *(const float4*)(X + (size_t)gr * 128 + k);
        f16x4 h, l;
        float vv[4] = {v.x, v.y, v.z, v.w};
        #pragma unroll
        for (int j = 0; j < 4; ++j) {
            _Float16 hj = (_Float16)vv[j];
            h[j] = hj;
            l[j] = (_Float16)(vv[j] - (float)hj);
        }
        *(f16x4*)&xh[row][k] = h;
        *(f16x4*)&xl[row][k] = l;
    }
    __syncthreads();

    const int lane = tid & 63;
    const int wid  = tid >> 6;
    const int wr   = wid >> 1, wc = wid & 1;      // 2x2 wave grid, 32x32 wave tile
    const int r    = lane & 15, g = lane >> 4;

    // ---- hoist A fragments (shared across all 3 branches) ----
    f16x8 Ah[2][4], Al[2][4];
    #pragma unroll
    for (int m = 0; m < 2; ++m)
        #pragma unroll
        for (int kk = 0; kk < 4; ++kk) {
            int arow = wr * 32 + m * 16 + r;
            int k0   = kk * 32 + g * 8;
            Ah[m][kk] = *(const f16x8*)&xh[arow][k0];
            Al[m][kk] = *(const f16x8*)&xl[arow][k0];
        }

    for (int br = 0; br < 3; ++br) {
        if (br > 0) __syncthreads();              // prior branch's B reads done
        // ---- stage W tile (64 cols x 128 k), already f16 [col][k] in global ----
        const _Float16* wbh = Wt + (size_t)br * 2 * MPAD * 128;
        const _Float16* wbl = wbh + (size_t)MPAD * 128;
        #pragma unroll
        for (int i = 0; i < 4; ++i) {
            int idx = tid + i * 256;              // 0..1023
            int cl  = idx >> 4;
            int kc  = (idx & 15) * 8;
            *(f16x8*)&wh[cl][kc] = *(const f16x8*)&wbh[(size_t)(col0 + cl) * 128 + kc];
            *(f16x8*)&wl[cl][kc] = *(const f16x8*)&wbl[(size_t)(col0 + cl) * 128 + kc];
        }
        __syncthreads();

        f32x4 acc[2][2];
        #pragma unroll
        for (int m = 0; m < 2; ++m)
            #pragma unroll
            for (int n = 0; n < 2; ++n)
                acc[m][n] = (f32x4){0.f, 0.f, 0.f, 0.f};

        #pragma unroll
        for (int n = 0; n < 2; ++n) {
            #pragma unroll
            for (int kk = 0; kk < 4; ++kk) {
                int bcol = wc * 32 + n * 16 + r;
                int k0   = kk * 32 + g * 8;
                f16x8 Bh = *(const f16x8*)&wh[bcol][k0];
                f16x8 Bl = *(const f16x8*)&wl[bcol][k0];
                #pragma unroll
                for (int m = 0; m < 2; ++m) {
                    acc[m][n] = __builtin_amdgcn_mfma_f32_16x16x32_f16(Ah[m][kk], Bh, acc[m][n], 0, 0, 0);
                    acc[m][n] = __builtin_amdgcn_mfma_f32_16x16x32_f16(Ah[m][kk], Bl, acc[m][n], 0, 0, 0);
                    acc[m][n] = __builtin_amdgcn_mfma_f32_16x16x32_f16(Al[m][kk], Bh, acc[m][n], 0, 0, 0);
                }
            }
        }

        float* outp = (br == 0) ? out0 : ((br == 1) ? out1 : out2);
        #pragma unroll
        for (int m = 0; m < 2; ++m)
            #pragma unroll
            for (int n = 0; n < 2; ++n) {
                int col = col0 + wc * 32 + n * 16 + r;
                if (col >= M) continue;
                float bs = 0.f;
                if (br == 0) bs = b0[col] + b1[col] + b2[col];
                #pragma unroll
                for (int i = 0; i < 4; ++i) {
                    int row = row0 + wr * 32 + m * 16 + g * 4 + i;
                    if (row < nrows)
                        outp[(size_t)row * M + col] = acc[m][n][i] + bs;
                }
            }
    }
}

// ---------------- CSR build ----------------
__global__ void zero_i32(int* __restrict__ p, int n)
{
    int i = blockIdx.x * blockDim.x + threadIdx.x;
    if (i < n) p[i] = 0;
}

__global__ void hist_dst(const int* __restrict__ ei, int E, int* __restrict__ cnt)
{
    int e = blockIdx.x * blockDim.x + threadIdx.x;
    if (e < E) atomicAdd(&cnt[ei[E + e]], 1);
}

__global__ void scan_phase1(const int* __restrict__ cnt, int ncnt, int* __restrict__ bsums, int n)
{
    __shared__ int s[256];
    int tid = threadIdx.x;
    int i = blockIdx.x * 256 + tid;
    int v = (i < n && i < ncnt) ? cnt[i] : 0;
    s[tid] = v; __syncthreads();
    for (int off = 128; off; off >>= 1) {
        if (tid < off) s[tid] += s[tid + off];
        __syncthreads();
    }
    if (tid == 0) bsums[blockIdx.x] = s[0];
}

__global__ void scan_phase2(int* __restrict__ bsums, int nb)
{
    __shared__ int s[256];
    int tid = threadIdx.x;
    int v = (tid < nb) ? bsums[tid] : 0;
    s[tid] = v; __syncthreads();
    for (int off = 1; off < 256; off <<= 1) {
        int t = (tid >= off) ? s[tid - off] : 0;
        __syncthreads();
        s[tid] += t;
        __syncthreads();
    }
    if (tid < nb) bsums[tid] = s[tid] - v;   // exclusive
}

__global__ void scan_phase3(const int* __restrict__ cnt, int ncnt,
                            const int* __restrict__ bsums, int* __restrict__ row_ptr, int n)
{
    __shared__ int s[256];
    int tid = threadIdx.x;
    int i = blockIdx.x * 256 + tid;
    int v = (i < n && i < ncnt) ? cnt[i] : 0;
    s[tid] = v; __syncthreads();
    for (int off = 1; off < 256; off <<= 1) {
        int t = (tid >= off) ? s[tid - off] : 0;
        __syncthreads();
        s[tid] += t;
        __syncthreads();
    }
    if (i < n) row_ptr[i] = s[tid] - v + bsums[blockIdx.x];
}

__global__ void fill_eids(const int* __restrict__ ei, int E,
                          const int* __restrict__ row_ptr, int* __restrict__ cur,
                          int* __restrict__ eids)
{
    int e = blockIdx.x * blockDim.x + threadIdx.x;
    if (e >= E) return;
    int d = ei[E + e];
    int p = row_ptr[d] + atomicAdd(&cur[d], 1);
    eids[p] = e;
}

__global__ void sort_rows(const int* __restrict__ row_ptr, int* __restrict__ eids, int N)
{
    int r = blockIdx.x * blockDim.x + threadIdx.x;
    if (r >= N) return;
    int b = row_ptr[r], e = row_ptr[r + 1];
    for (int i = b + 1; i < e; ++i) {
        int v = eids[i];
        int j = i - 1;
        while (j >= b && eids[j] > v) { eids[j + 1] = eids[j]; --j; }
        eids[j + 1] = v;
    }
}

__global__ void permute_edges(const int* __restrict__ eids, const int* __restrict__ ei,
                              const float* __restrict__ ew, int E,
                              int* __restrict__ srcp, float* __restrict__ wp)
{
    int i = blockIdx.x * blockDim.x + threadIdx.x;
    if (i >= E) return;
    int e = eids[i];
    srcp[i] = ei[e];
    wp[i]   = ew[e];
}

// ---------------- gather: out[d] += sum_e w[e]*h[src[e]] ----------------
__global__ __launch_bounds__(256)
void gather_add128(const float* __restrict__ h, const int* __restrict__ row_ptr,
                   const int* __restrict__ srcp, const float* __restrict__ wp,
                   float* __restrict__ out, int N)
{
    int row = blockIdx.x * 8 + (threadIdx.x >> 5);
    if (row >= N) return;
    int lane = threadIdx.x & 31;
    int beg = row_ptr[row], end = row_ptr[row + 1];
    float4 a0 = make_float4(0.f,0.f,0.f,0.f);
    float4 a1 = make_float4(0.f,0.f,0.f,0.f);
    int i = beg;
    for (; i + 2 <= end; i += 2) {
        int   s0 = srcp[i],  s1 = srcp[i + 1];
        float w0 = wp[i],    w1 = wp[i + 1];
        float4 v0 = *(const float4*)(h + (size_t)s0 * 128 + lane * 4);
        float4 v1 = *(const float4*)(h + (size_t)s1 * 128 + lane * 4);
        a0.x = fmaf(w0, v0.x, a0.x); a0.y = fmaf(w0, v0.y, a0.y);
        a0.z = fmaf(w0, v0.z, a0.z); a0.w = fmaf(w0, v0.w, a0.w);
        a1.x = fmaf(w1, v1.x, a1.x); a1.y = fmaf(w1, v1.y, a1.y);
        a1.z = fmaf(w1, v1.z, a1.z); a1.w = fmaf(w1, v1.w, a1.w);
    }
    if (i < end) {
        int   s0 = srcp[i];
        float w0 = wp[i];
        float4 v0 = *(const float4*)(h + (size_t)s0 * 128 + lane * 4);
        a0.x = fmaf(w0, v0.x, a0.x); a0.y = fmaf(w0, v0.y, a0.y);
        a0.z = fmaf(w0, v0.z, a0.z); a0.w = fmaf(w0, v0.w, a0.w);
    }
    float* o = out + (size_t)row * 128 + lane * 4;
    float4 c = *(float4*)o;
    c.x += a0.x + a1.x; c.y += a0.y + a1.y;
    c.z += a0.z + a1.z; c.w += a0.w + a1.w;
    *(float4*)o = c;
}

__global__ __launch_bounds__(256)
void gather_add40(const float* __restrict__ h, const int* __restrict__ row_ptr,
                  const int* __restrict__ srcp, const float* __restrict__ wp,
                  float* __restrict__ out, int N)
{
    int row = blockIdx.x * 16 + (threadIdx.x >> 4);
    int lane = threadIdx.x & 15;
    if (row >= N || lane >= 10) return;
    int beg = row_ptr[row], end = row_ptr[row + 1];
    float4 a0 = make_float4(0.f,0.f,0.f,0.f);
    float4 a1 = make_float4(0.f,0.f,0.f,0.f);
    int i = beg;
    for (; i + 2 <= end; i += 2) {
        int   s0 = srcp[i],  s1 = srcp[i + 1];
        float w0 = wp[i],    w1 = wp[i + 1];
        float4 v0 = *(const float4*)(h + (size_t)s0 * 40 + lane * 4);
        float4 v1 = *(const float4*)(h + (size_t)s1 * 40 + lane * 4);
        a0.x = fmaf(w0, v0.x, a0.x); a0.y = fmaf(w0, v0.y, a0.y);
        a0.z = fmaf(w0, v0.z, a0.z); a0.w = fmaf(w0, v0.w, a0.w);
        a1.x = fmaf(w1, v1.x, a1.x); a1.y = fmaf(w1, v1.y, a1.y);
        a1.z = fmaf(w1, v1.z, a1.z); a1.w = fmaf(w1, v1.w, a1.w);
    }
    if (i < end) {
        int   s0 = srcp[i];
        float w0 = wp[i];
        float4 v0 = *(const float4*)(h + (size_t)s0 * 40 + lane * 4);
        a0.x = fmaf(w0, v0.x, a0.x); a0.y = fmaf(w0, v0.y, a0.y);
        a0.z = fmaf(w0, v0.z, a0.z); a0.w = fmaf(w0, v0.w, a0.w);
    }
    float* o = out + (size_t)row * 40 + lane * 4;
    float4 c = *(float4*)o;
    c.x += a0.x + a1.x; c.y += a0.y + a1.y;
    c.z += a0.z + a1.z; c.w += a0.w + a1.w;
    *(float4*)o = c;
}

// ---------------- log_softmax over 40 cols, one wave per row ----------------
__global__ __launch_bounds__(256)
void logsoftmax40(const float* __restrict__ in, float* __restrict__ out, int nrows)
{
    int wave = threadIdx.x >> 6;
    int lane = threadIdx.x & 63;
    int r = blockIdx.x * 4 + wave;
    if (r >= nrows) return;
    float v = (lane < 40) ? in[(size_t)r * 40 + lane] : -INFINITY;
    float m = v;
    #pragma unroll
    for (int off = 32; off; off >>= 1) m = fmaxf(m, __shfl_xor(m, off, 64));
    float e = (lane < 40) ? expf(v - m) : 0.f;
    float s = e;
    #pragma unroll
    for (int off = 32; off; off >>= 1) s += __shfl_xor(s, off, 64);
    if (lane < 40) out[(size_t)r * 40 + lane] = v - m - logf(s);
}

// ---------------- launch ----------------
extern "C" void kernel_launch(void* const* d_in, const int* in_sizes, int n_in,
                              void* d_out, int out_size, void* d_ws, size_t ws_size,
                              hipStream_t stream)
{
    const float* x    = (const float*)d_in[0];
    const int*   ei1  = (const int*)  d_in[1];
    const float* ew1  = (const float*)d_in[2];
    const int*   ei2  = (const int*)  d_in[3];
    const float* ew2  = (const float*)d_in[4];

    const float* W_ln1 = (const float*)d_in[5];   const float* b_ln1 = (const float*)d_in[6];
    const float* W_c11 = (const float*)d_in[7];   const float* b_c11 = (const float*)d_in[8];
    const float* W_c21 = (const float*)d_in[9];   const float* b_c21 = (const float*)d_in[10];
    const float* W_ln2 = (const float*)d_in[11];  const float* b_ln2 = (const float*)d_in[12];
    const float* W_c12 = (const float*)d_in[13];  const float* b_c12 = (const float*)d_in[14];
    const float* W_c22 = (const float*)d_in[15];  const float* b_c22 = (const float*)d_in[16];
    const float* W_ln3 = (const float*)d_in[17];  const float* b_ln3 = (const float*)d_in[18];
    const float* W_c13 = (const float*)d_in[19];  const float* b_c13 = (const float*)d_in[20];
    const float* W_c23 = (const float*)d_in[21];  const float* b_c23 = (const float*)d_in[22];

    const int N = in_sizes[0] / 128;   // 50000
    const int E = in_sizes[2];         // 600000

    // ---- workspace layout ----
    auto align_up = [](size_t v) { return (v + 255) & ~(size_t)255; };
    char* base = (char*)d_ws;
    size_t off = 0;
    auto take = [&](size_t bytes) { char* p = base + off; off += align_up(bytes); return p; };

    float* xA  = (float*)take((size_t)N * 128 * 4);
    float* xB  = (float*)take((size_t)N * 128 * 4);
    float* hc1 = (float*)take((size_t)N * 128 * 4);
    float* hc2 = (float*)take((size_t)N * 128 * 4);

    _Float16* Wt1 = (_Float16*)take((size_t)3 * 2 * 128 * 128 * 2);
    _Float16* Wt2 = (_Float16*)take((size_t)3 * 2 * 128 * 128 * 2);
    _Float16* Wt3 = (_Float16*)take((size_t)3 * 2 * 64 * 128 * 2);

    int* cnt[2];  int* row_ptr[2];  int* eids[2];  int* srcp[2];  float* wp[2];  int* bsums[2];
    for (int s = 0; s < 2; ++s) {
        cnt[s]     = (int*)  take((size_t)N * 4);
        row_ptr[s] = (int*)  take((size_t)(N + 1) * 4);
        eids[s]    = (int*)  take((size_t)E * 4);
        srcp[s]    = (int*)  take((size_t)E * 4);
        wp[s]      = (float*)take((size_t)E * 4);
        bsums[s]   = (int*)  take(256 * 4);
    }

    dim3 blk(256);
    const int gN  = (N + 255) / 256;
    const int gN1 = (N + 1 + 255) / 256;
    const int gE  = (E + 255) / 256;
    dim3 gg3_128((N + 63) / 64, 2);
    dim3 gg3_40((N + 63) / 64, 1);
    dim3 gg128((N + 7) / 8);
    dim3 gg40((N + 15) / 16);
    dim3 gls((N + 3) / 4);

    // ---- W preprocessing: split+transpose into f16 hi/lo ----
    {
        const float* Ws1[3] = { W_ln1, W_c11, W_c21 };
        const float* Ws2[3] = { W_ln2, W_c12, W_c22 };
        const float* Ws3[3] = { W_ln3, W_c13, W_c23 };
        for (int b = 0; b < 3; ++b) {
            wsplit<<<(128 * 128 + 255) / 256, blk, 0, stream>>>(Ws1[b], Wt1 + (size_t)b * 2 * 128 * 128, 128, 128);
            wsplit<<<(128 * 128 + 255) / 256, blk, 0, stream>>>(Ws2[b], Wt2 + (size_t)b * 2 * 128 * 128, 128, 128);
            wsplit<<<(64 * 128 + 255) / 256, blk, 0, stream>>>(Ws3[b], Wt3 + (size_t)b * 2 * 64 * 128, 40, 64);
        }
    }

    // ---- build CSR for both edge sets ----
    const int* eis[2] = { ei1, ei2 };
    const float* ews[2] = { ew1, ew2 };
    for (int s = 0; s < 2; ++s) {
        zero_i32<<<gN, blk, 0, stream>>>(cnt[s], N);
        hist_dst<<<gE, blk, 0, stream>>>(eis[s], E, cnt[s]);
        scan_phase1<<<gN1, blk, 0, stream>>>(cnt[s], N, bsums[s], N + 1);
        scan_phase2<<<1, blk, 0, stream>>>(bsums[s], gN1);
        scan_phase3<<<gN1, blk, 0, stream>>>(cnt[s], N, bsums[s], row_ptr[s], N + 1);
        zero_i32<<<gN, blk, 0, stream>>>(cnt[s], N);
        fill_eids<<<gE, blk, 0, stream>>>(eis[s], E, row_ptr[s], cnt[s], eids[s]);
        sort_rows<<<gN, blk, 0, stream>>>(row_ptr[s], eids[s], N);
        permute_edges<<<gE, blk, 0, stream>>>(eids[s], eis[s], ews[s], E, srcp[s], wp[s]);
    }

    // ---- Block 1: x -> xA ----
    gemm3<128><<<gg3_128, blk, 0, stream>>>(x, Wt1, b_ln1, b_c11, b_c21, xA, hc1, hc2, 128, N);
    gather_add128<<<gg128, blk, 0, stream>>>(hc1, row_ptr[0], srcp[0], wp[0], xA, N);
    gather_add128<<<gg128, blk, 0, stream>>>(hc2, row_ptr[1], srcp[1], wp[1], xA, N);

    // ---- Block 2: xA -> xB ----
    gemm3<128><<<gg3_128, blk, 0, stream>>>(xA, Wt2, b_ln2, b_c12, b_c22, xB, hc1, hc2, 128, N);
    gather_add128<<<gg128, blk, 0, stream>>>(hc1, row_ptr[0], srcp[0], wp[0], xB, N);
    gather_add128<<<gg128, blk, 0, stream>>>(hc2, row_ptr[1], srcp[1], wp[1], xB, N);

    // ---- Block 3: xB -> xA (width 40) ----
    gemm3<64><<<gg3_40, blk, 0, stream>>>(xB, Wt3, b_ln3, b_c13, b_c23, xA, hc1, hc2, 40, N);
    gather_add40<<<gg40, blk, 0, stream>>>(hc1, row_ptr[0], srcp[0], wp[0], xA, N);
    gather_add40<<<gg40, blk, 0, stream>>>(hc2, row_ptr[1], srcp[1], wp[1], xA, N);

    // ---- log_softmax -> d_out ----
    logsoftmax40<<<gls, blk, 0, stream>>>(xA, (float*)d_out, N);
}

// Round 4
// 497.513 us; speedup vs baseline: 10.3131x; 1.1623x over previous
//
#include <hip/hip_runtime.h>
#include <math.h>

typedef _Float16 f16x8 __attribute__((ext_vector_type(8)));
typedef _Float16 f16x4 __attribute__((ext_vector_type(4)));
typedef float    f32x4 __attribute__((ext_vector_type(4)));

// ---------------- W preprocess: 3 matrices f32 [k][col] -> f16 hi/lo, [col][k] ----------------
__global__ void wsplit3(const float* __restrict__ W0, const float* __restrict__ W1,
                        const float* __restrict__ W2, _Float16* __restrict__ dst,
                        int M, int MPAD)
{
    int b = blockIdx.y;
    const float* W = (b == 0) ? W0 : ((b == 1) ? W1 : W2);
    _Float16* d = dst + (size_t)b * 2 * MPAD * 128;
    int idx = blockIdx.x * 256 + threadIdx.x;
    if (idx >= MPAD * 128) return;
    int col = idx >> 7, k = idx & 127;
    float v = (col < M) ? W[(size_t)k * M + col] : 0.f;
    _Float16 h = (_Float16)v;
    d[(size_t)col * 128 + k] = h;
    d[(size_t)MPAD * 128 + (size_t)col * 128 + k] = (_Float16)(v - (float)h);
}

// ---------------- fused 3-branch GEMM, split-f16 MFMA, W from L2 ----------------
// branch 0 -> f32 out0 (+ b0+b1+b2); branches 1,2 -> f16 out1/out2.
template<int MPAD>
__global__ __launch_bounds__(256)
void gemm3(const float* __restrict__ X, const _Float16* __restrict__ Wt,
           const float* __restrict__ b0, const float* __restrict__ b1,
           const float* __restrict__ b2,
           float* __restrict__ out0, _Float16* __restrict__ out1, _Float16* __restrict__ out2,
           int M, int nrows)
{
    constexpr int KP = 136;                       // 128 + 8 f16 pad
    __shared__ _Float16 xh[64][KP], xl[64][KP];

    const int tid  = threadIdx.x;
    const int row0 = blockIdx.x * 64;
    const int col0 = blockIdx.y * 64;

    // ---- stage X tile (64 rows x 128 k), split f32 -> f16 hi/lo ----
    #pragma unroll
    for (int i = 0; i < 8; ++i) {
        int idx = tid + i * 256;
        int row = idx >> 5;
        int k   = (idx & 31) * 4;
        int gr  = row0 + row;
        float4 v = make_float4(0.f, 0.f, 0.f, 0.f);
        if (gr < nrows) v = *(const float4*)(X + (size_t)gr * 128 + k);
        f16x4 h, l;
        float vv[4] = {v.x, v.y, v.z, v.w};
        #pragma unroll
        for (int j = 0; j < 4; ++j) {
            _Float16 hj = (_Float16)vv[j];
            h[j] = hj;
            l[j] = (_Float16)(vv[j] - (float)hj);
        }
        *(f16x4*)&xh[row][k] = h;
        *(f16x4*)&xl[row][k] = l;
    }
    __syncthreads();

    const int lane = tid & 63;
    const int wid  = tid >> 6;
    const int wr   = wid >> 1, wc = wid & 1;      // 2x2 wave grid, 32x32 wave tile
    const int r    = lane & 15, g = lane >> 4;

    // ---- hoist A fragments (shared across all 3 branches) ----
    f16x8 Ah[2][4], Al[2][4];
    #pragma unroll
    for (int m = 0; m < 2; ++m)
        #pragma unroll
        for (int kk = 0; kk < 4; ++kk) {
            int arow = wr * 32 + m * 16 + r;
            int k0   = kk * 32 + g * 8;
            Ah[m][kk] = *(const f16x8*)&xh[arow][k0];
            Al[m][kk] = *(const f16x8*)&xl[arow][k0];
        }

    #pragma unroll
    for (int br = 0; br < 3; ++br) {
        const _Float16* wbh = Wt + (size_t)br * 2 * MPAD * 128;
        const _Float16* wbl = wbh + (size_t)MPAD * 128;

        f32x4 acc[2][2];
        #pragma unroll
        for (int m = 0; m < 2; ++m)
            #pragma unroll
            for (int n = 0; n < 2; ++n)
                acc[m][n] = (f32x4){0.f, 0.f, 0.f, 0.f};

        #pragma unroll
        for (int n = 0; n < 2; ++n) {
            int bcol = col0 + wc * 32 + n * 16 + r;
            #pragma unroll
            for (int kk = 0; kk < 4; ++kk) {
                int k0 = kk * 32 + g * 8;
                f16x8 Bh = *(const f16x8*)&wbh[(size_t)bcol * 128 + k0];
                f16x8 Bl = *(const f16x8*)&wbl[(size_t)bcol * 128 + k0];
                #pragma unroll
                for (int m = 0; m < 2; ++m) {
                    acc[m][n] = __builtin_amdgcn_mfma_f32_16x16x32_f16(Ah[m][kk], Bh, acc[m][n], 0, 0, 0);
                    acc[m][n] = __builtin_amdgcn_mfma_f32_16x16x32_f16(Ah[m][kk], Bl, acc[m][n], 0, 0, 0);
                    acc[m][n] = __builtin_amdgcn_mfma_f32_16x16x32_f16(Al[m][kk], Bh, acc[m][n], 0, 0, 0);
                }
            }
        }

        #pragma unroll
        for (int m = 0; m < 2; ++m)
            #pragma unroll
            for (int n = 0; n < 2; ++n) {
                int col = col0 + wc * 32 + n * 16 + r;
                if (col >= M) continue;
                if (br == 0) {
                    float bs = b0[col] + b1[col] + b2[col];
                    #pragma unroll
                    for (int i = 0; i < 4; ++i) {
                        int row = row0 + wr * 32 + m * 16 + g * 4 + i;
                        if (row < nrows)
                            out0[(size_t)row * M + col] = acc[m][n][i] + bs;
                    }
                } else {
                    _Float16* outp = (br == 1) ? out1 : out2;
                    #pragma unroll
                    for (int i = 0; i < 4; ++i) {
                        int row = row0 + wr * 32 + m * 16 + g * 4 + i;
                        if (row < nrows)
                            outp[(size_t)row * M + col] = (_Float16)acc[m][n][i];
                    }
                }
            }
    }
}

// ---------------- CSR build (both edge sets batched via blockIdx.y) ----------------
__global__ void zero2(int* __restrict__ a, int* __restrict__ b, int n)
{
    int i = blockIdx.x * 256 + threadIdx.x;
    if (i < n) { a[i] = 0; b[i] = 0; }
}

__global__ void hist2(const int* __restrict__ eiA, const int* __restrict__ eiB, int E,
                      int* __restrict__ cA, int* __restrict__ cB)
{
    int e = blockIdx.x * 256 + threadIdx.x;
    if (e >= E) return;
    if (blockIdx.y == 0) atomicAdd(&cA[eiA[E + e]], 1);
    else                 atomicAdd(&cB[eiB[E + e]], 1);
}

__global__ void scan1_2(const int* __restrict__ cA, const int* __restrict__ cB, int ncnt,
                        int* __restrict__ bsA, int* __restrict__ bsB, int n)
{
    const int* cnt = blockIdx.y ? cB : cA;
    int* bsums = blockIdx.y ? bsB : bsA;
    __shared__ int s[256];
    int tid = threadIdx.x;
    int i = blockIdx.x * 256 + tid;
    int v = (i < n && i < ncnt) ? cnt[i] : 0;
    s[tid] = v; __syncthreads();
    for (int off = 128; off; off >>= 1) {
        if (tid < off) s[tid] += s[tid + off];
        __syncthreads();
    }
    if (tid == 0) bsums[blockIdx.x] = s[0];
}

__global__ void scan2_2(int* __restrict__ bsA, int* __restrict__ bsB, int nb)
{
    int* bsums = blockIdx.y ? bsB : bsA;
    __shared__ int s[256];
    int tid = threadIdx.x;
    int v = (tid < nb) ? bsums[tid] : 0;
    s[tid] = v; __syncthreads();
    for (int off = 1; off < 256; off <<= 1) {
        int t = (tid >= off) ? s[tid - off] : 0;
        __syncthreads();
        s[tid] += t;
        __syncthreads();
    }
    if (tid < nb) bsums[tid] = s[tid] - v;   // exclusive
}

// also zeroes cnt (reused as fill cursor)
__global__ void scan3_2(int* __restrict__ cA, int* __restrict__ cB, int ncnt,
                        const int* __restrict__ bsA, const int* __restrict__ bsB,
                        int* __restrict__ rpA, int* __restrict__ rpB, int n)
{
    int* cnt = blockIdx.y ? cB : cA;
    const int* bsums = blockIdx.y ? bsB : bsA;
    int* row_ptr = blockIdx.y ? rpB : rpA;
    __shared__ int s[256];
    int tid = threadIdx.x;
    int i = blockIdx.x * 256 + tid;
    int v = (i < n && i < ncnt) ? cnt[i] : 0;
    s[tid] = v; __syncthreads();
    for (int off = 1; off < 256; off <<= 1) {
        int t = (tid >= off) ? s[tid - off] : 0;
        __syncthreads();
        s[tid] += t;
        __syncthreads();
    }
    if (i < n) {
        row_ptr[i] = s[tid] - v + bsums[blockIdx.x];
        if (i < ncnt) cnt[i] = 0;
    }
}

__global__ void fill2(const int* __restrict__ eiA, const int* __restrict__ eiB, int E,
                      const int* __restrict__ rpA, const int* __restrict__ rpB,
                      int* __restrict__ curA, int* __restrict__ curB,
                      int* __restrict__ edA, int* __restrict__ edB)
{
    int e = blockIdx.x * 256 + threadIdx.x;
    if (e >= E) return;
    const int* ei = blockIdx.y ? eiB : eiA;
    const int* rp = blockIdx.y ? rpB : rpA;
    int* cur = blockIdx.y ? curB : curA;
    int* eids = blockIdx.y ? edB : edA;
    int d = ei[E + e];
    int p = rp[d] + atomicAdd(&cur[d], 1);
    eids[p] = e;
}

__global__ void sort2(const int* __restrict__ rpA, const int* __restrict__ rpB,
                      int* __restrict__ edA, int* __restrict__ edB, int N)
{
    int r = blockIdx.x * 256 + threadIdx.x;
    if (r >= N) return;
    const int* rp = blockIdx.y ? rpB : rpA;
    int* eids = blockIdx.y ? edB : edA;
    int b = rp[r], e = rp[r + 1];
    for (int i = b + 1; i < e; ++i) {
        int v = eids[i];
        int j = i - 1;
        while (j >= b && eids[j] > v) { eids[j + 1] = eids[j]; --j; }
        eids[j + 1] = v;
    }
}

__global__ void permute2(const int* __restrict__ edA, const int* __restrict__ edB,
                         const int* __restrict__ eiA, const int* __restrict__ eiB,
                         const float* __restrict__ ewA, const float* __restrict__ ewB, int E,
                         int* __restrict__ sA, int* __restrict__ sB,
                         float* __restrict__ wA, float* __restrict__ wB)
{
    int i = blockIdx.x * 256 + threadIdx.x;
    if (i >= E) return;
    const int* eids = blockIdx.y ? edB : edA;
    const int* ei = blockIdx.y ? eiB : eiA;
    const float* ew = blockIdx.y ? ewB : ewA;
    int* srcp = blockIdx.y ? sB : sA;
    float* wp = blockIdx.y ? wB : wA;
    int e = eids[i];
    srcp[i] = ei[e];
    wp[i]   = ew[e];
}

// ---------------- fused dual gather: out[d] += sum(csr1: w*h1[s]) + sum(csr2: w*h2[s]) ----------------
__global__ __launch_bounds__(256)
void gather2_128(const _Float16* __restrict__ h1, const int* __restrict__ rp1,
                 const int* __restrict__ s1, const float* __restrict__ w1,
                 const _Float16* __restrict__ h2, const int* __restrict__ rp2,
                 const int* __restrict__ s2, const float* __restrict__ w2,
                 float* __restrict__ out, int N)
{
    int row = blockIdx.x * 8 + (threadIdx.x >> 5);
    if (row >= N) return;
    int lane = threadIdx.x & 31;
    float a0 = 0.f, a1 = 0.f, a2 = 0.f, a3 = 0.f;

    #pragma unroll
    for (int set = 0; set < 2; ++set) {
        const _Float16* h = set ? h2 : h1;
        const int* rp = set ? rp2 : rp1;
        const int* sp = set ? s2 : s1;
        const float* wp = set ? w2 : w1;
        int beg = rp[row], end = rp[row + 1];
        int i = beg;
        for (; i + 2 <= end; i += 2) {
            int   sa = sp[i],  sb = sp[i + 1];
            float wa = wp[i],  wb = wp[i + 1];
            f16x4 va = *(const f16x4*)(h + (size_t)sa * 128 + lane * 4);
            f16x4 vb = *(const f16x4*)(h + (size_t)sb * 128 + lane * 4);
            a0 = fmaf(wa, (float)va[0], a0); a1 = fmaf(wa, (float)va[1], a1);
            a2 = fmaf(wa, (float)va[2], a2); a3 = fmaf(wa, (float)va[3], a3);
            a0 = fmaf(wb, (float)vb[0], a0); a1 = fmaf(wb, (float)vb[1], a1);
            a2 = fmaf(wb, (float)vb[2], a2); a3 = fmaf(wb, (float)vb[3], a3);
        }
        if (i < end) {
            int   sa = sp[i];
            float wa = wp[i];
            f16x4 va = *(const f16x4*)(h + (size_t)sa * 128 + lane * 4);
            a0 = fmaf(wa, (float)va[0], a0); a1 = fmaf(wa, (float)va[1], a1);
            a2 = fmaf(wa, (float)va[2], a2); a3 = fmaf(wa, (float)va[3], a3);
        }
    }
    float* o = out + (size_t)row * 128 + lane * 4;
    float4 c = *(float4*)o;
    c.x += a0; c.y += a1; c.z += a2; c.w += a3;
    *(float4*)o = c;
}

__global__ __launch_bounds__(256)
void gather2_40(const _Float16* __restrict__ h1, const int* __restrict__ rp1,
                const int* __restrict__ s1, const float* __restrict__ w1,
                const _Float16* __restrict__ h2, const int* __restrict__ rp2,
                const int* __restrict__ s2, const float* __restrict__ w2,
                float* __restrict__ out, int N)
{
    int row = blockIdx.x * 16 + (threadIdx.x >> 4);
    int lane = threadIdx.x & 15;
    if (row >= N || lane >= 10) return;
    float a0 = 0.f, a1 = 0.f, a2 = 0.f, a3 = 0.f;

    #pragma unroll
    for (int set = 0; set < 2; ++set) {
        const _Float16* h = set ? h2 : h1;
        const int* rp = set ? rp2 : rp1;
        const int* sp = set ? s2 : s1;
        const float* wp = set ? w2 : w1;
        int beg = rp[row], end = rp[row + 1];
        int i = beg;
        for (; i + 2 <= end; i += 2) {
            int   sa = sp[i],  sb = sp[i + 1];
            float wa = wp[i],  wb = wp[i + 1];
            f16x4 va = *(const f16x4*)(h + (size_t)sa * 40 + lane * 4);
            f16x4 vb = *(const f16x4*)(h + (size_t)sb * 40 + lane * 4);
            a0 = fmaf(wa, (float)va[0], a0); a1 = fmaf(wa, (float)va[1], a1);
            a2 = fmaf(wa, (float)va[2], a2); a3 = fmaf(wa, (float)va[3], a3);
            a0 = fmaf(wb, (float)vb[0], a0); a1 = fmaf(wb, (float)vb[1], a1);
            a2 = fmaf(wb, (float)vb[2], a2); a3 = fmaf(wb, (float)vb[3], a3);
        }
        if (i < end) {
            int   sa = sp[i];
            float wa = wp[i];
            f16x4 va = *(const f16x4*)(h + (size_t)sa * 40 + lane * 4);
            a0 = fmaf(wa, (float)va[0], a0); a1 = fmaf(wa, (float)va[1], a1);
            a2 = fmaf(wa, (float)va[2], a2); a3 = fmaf(wa, (float)va[3], a3);
        }
    }
    float* o = out + (size_t)row * 40 + lane * 4;
    float4 c = *(float4*)o;
    c.x += a0; c.y += a1; c.z += a2; c.w += a3;
    *(float4*)o = c;
}

// ---------------- log_softmax over 40 cols, one wave per row ----------------
__global__ __launch_bounds__(256)
void logsoftmax40(const float* __restrict__ in, float* __restrict__ out, int nrows)
{
    int wave = threadIdx.x >> 6;
    int lane = threadIdx.x & 63;
    int r = blockIdx.x * 4 + wave;
    if (r >= nrows) return;
    float v = (lane < 40) ? in[(size_t)r * 40 + lane] : -INFINITY;
    float m = v;
    #pragma unroll
    for (int off = 32; off; off >>= 1) m = fmaxf(m, __shfl_xor(m, off, 64));
    float e = (lane < 40) ? expf(v - m) : 0.f;
    float s = e;
    #pragma unroll
    for (int off = 32; off; off >>= 1) s += __shfl_xor(s, off, 64);
    if (lane < 40) out[(size_t)r * 40 + lane] = v - m - logf(s);
}

// ---------------- launch ----------------
extern "C" void kernel_launch(void* const* d_in, const int* in_sizes, int n_in,
                              void* d_out, int out_size, void* d_ws, size_t ws_size,
                              hipStream_t stream)
{
    const float* x    = (const float*)d_in[0];
    const int*   ei1  = (const int*)  d_in[1];
    const float* ew1  = (const float*)d_in[2];
    const int*   ei2  = (const int*)  d_in[3];
    const float* ew2  = (const float*)d_in[4];

    const float* W_ln1 = (const float*)d_in[5];   const float* b_ln1 = (const float*)d_in[6];
    const float* W_c11 = (const float*)d_in[7];   const float* b_c11 = (const float*)d_in[8];
    const float* W_c21 = (const float*)d_in[9];   const float* b_c21 = (const float*)d_in[10];
    const float* W_ln2 = (const float*)d_in[11];  const float* b_ln2 = (const float*)d_in[12];
    const float* W_c12 = (const float*)d_in[13];  const float* b_c12 = (const float*)d_in[14];
    const float* W_c22 = (const float*)d_in[15];  const float* b_c22 = (const float*)d_in[16];
    const float* W_ln3 = (const float*)d_in[17];  const float* b_ln3 = (const float*)d_in[18];
    const float* W_c13 = (const float*)d_in[19];  const float* b_c13 = (const float*)d_in[20];
    const float* W_c23 = (const float*)d_in[21];  const float* b_c23 = (const float*)d_in[22];

    const int N = in_sizes[0] / 128;   // 50000
    const int E = in_sizes[2];         // 600000

    // ---- workspace layout ----
    auto align_up = [](size_t v) { return (v + 255) & ~(size_t)255; };
    char* base = (char*)d_ws;
    size_t off = 0;
    auto take = [&](size_t bytes) { char* p = base + off; off += align_up(bytes); return p; };

    float*    xA  = (float*)   take((size_t)N * 128 * 4);
    float*    xB  = (float*)   take((size_t)N * 128 * 4);
    _Float16* hc1 = (_Float16*)take((size_t)N * 128 * 2);
    _Float16* hc2 = (_Float16*)take((size_t)N * 128 * 2);

    _Float16* Wt1 = (_Float16*)take((size_t)3 * 2 * 128 * 128 * 2);
    _Float16* Wt2 = (_Float16*)take((size_t)3 * 2 * 128 * 128 * 2);
    _Float16* Wt3 = (_Float16*)take((size_t)3 * 2 * 64 * 128 * 2);

    int* cnt[2];  int* row_ptr[2];  int* eids[2];  int* srcp[2];  float* wp[2];  int* bsums[2];
    for (int s = 0; s < 2; ++s) {
        cnt[s]     = (int*)  take((size_t)N * 4);
        row_ptr[s] = (int*)  take((size_t)(N + 1) * 4);
        eids[s]    = (int*)  take((size_t)E * 4);
        srcp[s]    = (int*)  take((size_t)E * 4);
        wp[s]      = (float*)take((size_t)E * 4);
        bsums[s]   = (int*)  take(256 * 4);
    }

    dim3 blk(256);
    const int gN  = (N + 255) / 256;
    const int gN1 = (N + 1 + 255) / 256;
    const int gE  = (E + 255) / 256;
    dim3 gg3_128((N + 63) / 64, 2);
    dim3 gg3_40((N + 63) / 64, 1);
    dim3 gg128((N + 7) / 8);
    dim3 gg40((N + 15) / 16);
    dim3 gls((N + 3) / 4);

    // ---- W preprocessing (3 launches) ----
    wsplit3<<<dim3((128 * 128 + 255) / 256, 3), blk, 0, stream>>>(W_ln1, W_c11, W_c21, Wt1, 128, 128);
    wsplit3<<<dim3((128 * 128 + 255) / 256, 3), blk, 0, stream>>>(W_ln2, W_c12, W_c22, Wt2, 128, 128);
    wsplit3<<<dim3((64 * 128 + 255) / 256, 3), blk, 0, stream>>>(W_ln3, W_c13, W_c23, Wt3, 40, 64);

    // ---- build CSR for both edge sets (8 launches) ----
    zero2<<<gN, blk, 0, stream>>>(cnt[0], cnt[1], N);
    hist2<<<dim3(gE, 2), blk, 0, stream>>>(ei1, ei2, E, cnt[0], cnt[1]);
    scan1_2<<<dim3(gN1, 2), blk, 0, stream>>>(cnt[0], cnt[1], N, bsums[0], bsums[1], N + 1);
    scan2_2<<<dim3(1, 2), blk, 0, stream>>>(bsums[0], bsums[1], gN1);
    scan3_2<<<dim3(gN1, 2), blk, 0, stream>>>(cnt[0], cnt[1], N, bsums[0], bsums[1],
                                              row_ptr[0], row_ptr[1], N + 1);
    fill2<<<dim3(gE, 2), blk, 0, stream>>>(ei1, ei2, E, row_ptr[0], row_ptr[1],
                                           cnt[0], cnt[1], eids[0], eids[1]);
    sort2<<<dim3(gN, 2), blk, 0, stream>>>(row_ptr[0], row_ptr[1], eids[0], eids[1], N);
    permute2<<<dim3(gE, 2), blk, 0, stream>>>(eids[0], eids[1], ei1, ei2, ew1, ew2, E,
                                              srcp[0], srcp[1], wp[0], wp[1]);

    // ---- Block 1: x -> xA ----
    gemm3<128><<<gg3_128, blk, 0, stream>>>(x, Wt1, b_ln1, b_c11, b_c21, xA, hc1, hc2, 128, N);
    gather2_128<<<gg128, blk, 0, stream>>>(hc1, row_ptr[0], srcp[0], wp[0],
                                           hc2, row_ptr[1], srcp[1], wp[1], xA, N);

    // ---- Block 2: xA -> xB ----
    gemm3<128><<<gg3_128, blk, 0, stream>>>(xA, Wt2, b_ln2, b_c12, b_c22, xB, hc1, hc2, 128, N);
    gather2_128<<<gg128, blk, 0, stream>>>(hc1, row_ptr[0], srcp[0], wp[0],
                                           hc2, row_ptr[1], srcp[1], wp[1], xB, N);

    // ---- Block 3: xB -> xA (width 40) ----
    gemm3<64><<<gg3_40, blk, 0, stream>>>(xB, Wt3, b_ln3, b_c13, b_c23, xA, hc1, hc2, 40, N);
    gather2_40<<<gg40, blk, 0, stream>>>(hc1, row_ptr[0], srcp[0], wp[0],
                                         hc2, row_ptr[1], srcp[1], wp[1], xA, N);

    // ---- log_softmax -> d_out ----
    logsoftmax40<<<gls, blk, 0, stream>>>(xA, (float*)d_out, N);
}

// Round 5
// 448.997 us; speedup vs baseline: 11.4274x; 1.1081x over previous
//
#include <hip/hip_runtime.h>
#include <math.h>

typedef _Float16 f16x8 __attribute__((ext_vector_type(8)));
typedef _Float16 f16x4 __attribute__((ext_vector_type(4)));
typedef float    f32x4 __attribute__((ext_vector_type(4)));

// ---------------- W preprocess: 3 matrices f32 [k][col] -> f16 hi/lo, [col][k] ----------------
__global__ void wsplit3(const float* __restrict__ W0, const float* __restrict__ W1,
                        const float* __restrict__ W2, _Float16* __restrict__ dst,
                        int M, int MPAD)
{
    int b = blockIdx.y;
    const float* W = (b == 0) ? W0 : ((b == 1) ? W1 : W2);
    _Float16* d = dst + (size_t)b * 2 * MPAD * 128;
    int idx = blockIdx.x * 256 + threadIdx.x;
    if (idx >= MPAD * 128) return;
    int col = idx >> 7, k = idx & 127;
    float v = (col < M) ? W[(size_t)k * M + col] : 0.f;
    _Float16 h = (_Float16)v;
    d[(size_t)col * 128 + k] = h;
    d[(size_t)MPAD * 128 + (size_t)col * 128 + k] = (_Float16)(v - (float)h);
}

// ---------------- fused 3-branch GEMM, split-f16 MFMA, W from L2, full-width col tile ----
// NN = number of 16-col tiles per wave (4 -> 128 cols total, 2 -> 64 cols).
// branch 0 -> f32 out0 (+ b0+b1+b2); branches 1,2 -> f16 out1/out2.
template<int MPAD, int NN>
__global__ __launch_bounds__(256)
void gemm3(const float* __restrict__ X, const _Float16* __restrict__ Wt,
           const float* __restrict__ b0, const float* __restrict__ b1,
           const float* __restrict__ b2,
           float* __restrict__ out0, _Float16* __restrict__ out1, _Float16* __restrict__ out2,
           int M, int nrows)
{
    constexpr int KP = 136;                       // 128 + 8 f16 pad
    __shared__ _Float16 xh[64][KP], xl[64][KP];

    const int tid  = threadIdx.x;
    const int row0 = blockIdx.x * 64;

    // ---- stage X tile (64 rows x 128 k), split f32 -> f16 hi/lo ----
    #pragma unroll
    for (int i = 0; i < 8; ++i) {
        int idx = tid + i * 256;
        int row = idx >> 5;
        int k   = (idx & 31) * 4;
        int gr  = row0 + row;
        float4 v = make_float4(0.f, 0.f, 0.f, 0.f);
        if (gr < nrows) v = *(const float4*)(X + (size_t)gr * 128 + k);
        f16x4 h, l;
        float vv[4] = {v.x, v.y, v.z, v.w};
        #pragma unroll
        for (int j = 0; j < 4; ++j) {
            _Float16 hj = (_Float16)vv[j];
            h[j] = hj;
            l[j] = (_Float16)(vv[j] - (float)hj);
        }
        *(f16x4*)&xh[row][k] = h;
        *(f16x4*)&xl[row][k] = l;
    }
    __syncthreads();

    const int lane = tid & 63;
    const int wid  = tid >> 6;
    const int wr   = wid >> 1, wc = wid & 1;      // 2x2 wave grid
    const int r    = lane & 15, g = lane >> 4;

    // ---- hoist A fragments (shared across all 3 branches) ----
    f16x8 Ah[2][4], Al[2][4];
    #pragma unroll
    for (int m = 0; m < 2; ++m)
        #pragma unroll
        for (int kk = 0; kk < 4; ++kk) {
            int arow = wr * 32 + m * 16 + r;
            int k0   = kk * 32 + g * 8;
            Ah[m][kk] = *(const f16x8*)&xh[arow][k0];
            Al[m][kk] = *(const f16x8*)&xl[arow][k0];
        }

    #pragma unroll
    for (int br = 0; br < 3; ++br) {
        const _Float16* wbh = Wt + (size_t)br * 2 * MPAD * 128;
        const _Float16* wbl = wbh + (size_t)MPAD * 128;

        f32x4 acc[2][NN];
        #pragma unroll
        for (int m = 0; m < 2; ++m)
            #pragma unroll
            for (int n = 0; n < NN; ++n)
                acc[m][n] = (f32x4){0.f, 0.f, 0.f, 0.f};

        #pragma unroll
        for (int n = 0; n < NN; ++n) {
            int bcol = (n >> 1) * 64 + wc * 32 + (n & 1) * 16 + r;
            #pragma unroll
            for (int kk = 0; kk < 4; ++kk) {
                int k0 = kk * 32 + g * 8;
                f16x8 Bh = *(const f16x8*)&wbh[(size_t)bcol * 128 + k0];
                f16x8 Bl = *(const f16x8*)&wbl[(size_t)bcol * 128 + k0];
                #pragma unroll
                for (int m = 0; m < 2; ++m) {
                    acc[m][n] = __builtin_amdgcn_mfma_f32_16x16x32_f16(Ah[m][kk], Bh, acc[m][n], 0, 0, 0);
                    acc[m][n] = __builtin_amdgcn_mfma_f32_16x16x32_f16(Ah[m][kk], Bl, acc[m][n], 0, 0, 0);
                    acc[m][n] = __builtin_amdgcn_mfma_f32_16x16x32_f16(Al[m][kk], Bh, acc[m][n], 0, 0, 0);
                }
            }
        }

        #pragma unroll
        for (int m = 0; m < 2; ++m)
            #pragma unroll
            for (int n = 0; n < NN; ++n) {
                int col = (n >> 1) * 64 + wc * 32 + (n & 1) * 16 + r;
                if (col >= M) continue;
                if (br == 0) {
                    float bs = b0[col] + b1[col] + b2[col];
                    #pragma unroll
                    for (int i = 0; i < 4; ++i) {
                        int row = row0 + wr * 32 + m * 16 + g * 4 + i;
                        if (row < nrows)
                            out0[(size_t)row * M + col] = acc[m][n][i] + bs;
                    }
                } else {
                    _Float16* outp = (br == 1) ? out1 : out2;
                    #pragma unroll
                    for (int i = 0; i < 4; ++i) {
                        int row = row0 + wr * 32 + m * 16 + g * 4 + i;
                        if (row < nrows)
                            outp[(size_t)row * M + col] = (_Float16)acc[m][n][i];
                    }
                }
            }
    }
}

// ---------------- combined CSR build over both edge sets (2E edges) ----------------
__global__ void zero_i32(int* __restrict__ p, int n)
{
    int i = blockIdx.x * 256 + threadIdx.x;
    if (i < n) p[i] = 0;
}

__global__ void hist_c(const int* __restrict__ ei1, const int* __restrict__ ei2,
                       int E, int* __restrict__ cnt)
{
    int i = blockIdx.x * 256 + threadIdx.x;
    if (i >= 2 * E) return;
    int d = (i < E) ? ei1[E + i] : ei2[E + (i - E)];
    atomicAdd(&cnt[d], 1);
}

__global__ void scan_phase1(const int* __restrict__ cnt, int ncnt, int* __restrict__ bsums, int n)
{
    __shared__ int s[256];
    int tid = threadIdx.x;
    int i = blockIdx.x * 256 + tid;
    int v = (i < n && i < ncnt) ? cnt[i] : 0;
    s[tid] = v; __syncthreads();
    for (int off = 128; off; off >>= 1) {
        if (tid < off) s[tid] += s[tid + off];
        __syncthreads();
    }
    if (tid == 0) bsums[blockIdx.x] = s[0];
}

__global__ void scan_phase2(int* __restrict__ bsums, int nb)
{
    __shared__ int s[256];
    int tid = threadIdx.x;
    int v = (tid < nb) ? bsums[tid] : 0;
    s[tid] = v; __syncthreads();
    for (int off = 1; off < 256; off <<= 1) {
        int t = (tid >= off) ? s[tid - off] : 0;
        __syncthreads();
        s[tid] += t;
        __syncthreads();
    }
    if (tid < nb) bsums[tid] = s[tid] - v;   // exclusive
}

// also zeroes cnt (reused as fill cursor)
__global__ void scan_phase3(int* __restrict__ cnt, int ncnt,
                            const int* __restrict__ bsums, int* __restrict__ row_ptr, int n)
{
    __shared__ int s[256];
    int tid = threadIdx.x;
    int i = blockIdx.x * 256 + tid;
    int v = (i < n && i < ncnt) ? cnt[i] : 0;
    s[tid] = v; __syncthreads();
    for (int off = 1; off < 256; off <<= 1) {
        int t = (tid >= off) ? s[tid - off] : 0;
        __syncthreads();
        s[tid] += t;
        __syncthreads();
    }
    if (i < n) {
        row_ptr[i] = s[tid] - v + bsums[blockIdx.x];
        if (i < ncnt) cnt[i] = 0;
    }
}

// fill: write packed {src', w} (8B, nontemporal) directly at final CSR slot.
// set-2 sources encoded as src + N.
__global__ void fill_direct(const int* __restrict__ ei1, const float* __restrict__ ew1,
                            const int* __restrict__ ei2, const float* __restrict__ ew2,
                            int E, int N, const int* __restrict__ rp, int* __restrict__ cur,
                            long long* __restrict__ pack)
{
    int i = blockIdx.x * 256 + threadIdx.x;
    if (i >= 2 * E) return;
    int set = (i >= E);
    int e = set ? i - E : i;
    const int* ei = set ? ei2 : ei1;
    int d = ei[E + e];
    int s = ei[e] + set * N;
    float w = set ? ew2[e] : ew1[e];
    int p = rp[d] + atomicAdd(&cur[d], 1);
    long long v = ((long long)__float_as_int(w) << 32) | (unsigned)s;
    __builtin_nontemporal_store(v, &pack[p]);
}

// ---------------- combined gather: out[row] += sum_i w_i * hc[src'_i] ----------------
__global__ __launch_bounds__(256)
void gather_c128(const _Float16* __restrict__ hc, const int* __restrict__ rp,
                 const long long* __restrict__ pack, float* __restrict__ out, int N)
{
    int row = blockIdx.x * 8 + (threadIdx.x >> 5);
    if (row >= N) return;
    int lane = threadIdx.x & 31;
    int beg = rp[row], end = rp[row + 1];
    float a0 = 0.f, a1 = 0.f, a2 = 0.f, a3 = 0.f;
    int i = beg;
    for (; i + 2 <= end; i += 2) {
        long long q0 = pack[i], q1 = pack[i + 1];
        int   sa = (int)(unsigned)q0,          sb = (int)(unsigned)q1;
        float wa = __int_as_float((int)(q0 >> 32)), wb = __int_as_float((int)(q1 >> 32));
        f16x4 va = *(const f16x4*)(hc + (size_t)sa * 128 + lane * 4);
        f16x4 vb = *(const f16x4*)(hc + (size_t)sb * 128 + lane * 4);
        a0 = fmaf(wa, (float)va[0], a0); a1 = fmaf(wa, (float)va[1], a1);
        a2 = fmaf(wa, (float)va[2], a2); a3 = fmaf(wa, (float)va[3], a3);
        a0 = fmaf(wb, (float)vb[0], a0); a1 = fmaf(wb, (float)vb[1], a1);
        a2 = fmaf(wb, (float)vb[2], a2); a3 = fmaf(wb, (float)vb[3], a3);
    }
    if (i < end) {
        long long q0 = pack[i];
        int   sa = (int)(unsigned)q0;
        float wa = __int_as_float((int)(q0 >> 32));
        f16x4 va = *(const f16x4*)(hc + (size_t)sa * 128 + lane * 4);
        a0 = fmaf(wa, (float)va[0], a0); a1 = fmaf(wa, (float)va[1], a1);
        a2 = fmaf(wa, (float)va[2], a2); a3 = fmaf(wa, (float)va[3], a3);
    }
    float* o = out + (size_t)row * 128 + lane * 4;
    float4 c = *(float4*)o;
    c.x += a0; c.y += a1; c.z += a2; c.w += a3;
    *(float4*)o = c;
}

__global__ __launch_bounds__(256)
void gather_c40(const _Float16* __restrict__ hc, const int* __restrict__ rp,
                const long long* __restrict__ pack, float* __restrict__ out, int N)
{
    int row = blockIdx.x * 16 + (threadIdx.x >> 4);
    int lane = threadIdx.x & 15;
    if (row >= N || lane >= 10) return;
    int beg = rp[row], end = rp[row + 1];
    float a0 = 0.f, a1 = 0.f, a2 = 0.f, a3 = 0.f;
    int i = beg;
    for (; i + 2 <= end; i += 2) {
        long long q0 = pack[i], q1 = pack[i + 1];
        int   sa = (int)(unsigned)q0,          sb = (int)(unsigned)q1;
        float wa = __int_as_float((int)(q0 >> 32)), wb = __int_as_float((int)(q1 >> 32));
        f16x4 va = *(const f16x4*)(hc + (size_t)sa * 40 + lane * 4);
        f16x4 vb = *(const f16x4*)(hc + (size_t)sb * 40 + lane * 4);
        a0 = fmaf(wa, (float)va[0], a0); a1 = fmaf(wa, (float)va[1], a1);
        a2 = fmaf(wa, (float)va[2], a2); a3 = fmaf(wa, (float)va[3], a3);
        a0 = fmaf(wb, (float)vb[0], a0); a1 = fmaf(wb, (float)vb[1], a1);
        a2 = fmaf(wb, (float)vb[2], a2); a3 = fmaf(wb, (float)vb[3], a3);
    }
    if (i < end) {
        long long q0 = pack[i];
        int   sa = (int)(unsigned)q0;
        float wa = __int_as_float((int)(q0 >> 32));
        f16x4 va = *(const f16x4*)(hc + (size_t)sa * 40 + lane * 4);
        a0 = fmaf(wa, (float)va[0], a0); a1 = fmaf(wa, (float)va[1], a1);
        a2 = fmaf(wa, (float)va[2], a2); a3 = fmaf(wa, (float)va[3], a3);
    }
    float* o = out + (size_t)row * 40 + lane * 4;
    float4 c = *(float4*)o;
    c.x += a0; c.y += a1; c.z += a2; c.w += a3;
    *(float4*)o = c;
}

// ---------------- log_softmax over 40 cols, one wave per row ----------------
__global__ __launch_bounds__(256)
void logsoftmax40(const float* __restrict__ in, float* __restrict__ out, int nrows)
{
    int wave = threadIdx.x >> 6;
    int lane = threadIdx.x & 63;
    int r = blockIdx.x * 4 + wave;
    if (r >= nrows) return;
    float v = (lane < 40) ? in[(size_t)r * 40 + lane] : -INFINITY;
    float m = v;
    #pragma unroll
    for (int off = 32; off; off >>= 1) m = fmaxf(m, __shfl_xor(m, off, 64));
    float e = (lane < 40) ? expf(v - m) : 0.f;
    float s = e;
    #pragma unroll
    for (int off = 32; off; off >>= 1) s += __shfl_xor(s, off, 64);
    if (lane < 40) out[(size_t)r * 40 + lane] = v - m - logf(s);
}

// ---------------- launch ----------------
extern "C" void kernel_launch(void* const* d_in, const int* in_sizes, int n_in,
                              void* d_out, int out_size, void* d_ws, size_t ws_size,
                              hipStream_t stream)
{
    const float* x    = (const float*)d_in[0];
    const int*   ei1  = (const int*)  d_in[1];
    const float* ew1  = (const float*)d_in[2];
    const int*   ei2  = (const int*)  d_in[3];
    const float* ew2  = (const float*)d_in[4];

    const float* W_ln1 = (const float*)d_in[5];   const float* b_ln1 = (const float*)d_in[6];
    const float* W_c11 = (const float*)d_in[7];   const float* b_c11 = (const float*)d_in[8];
    const float* W_c21 = (const float*)d_in[9];   const float* b_c21 = (const float*)d_in[10];
    const float* W_ln2 = (const float*)d_in[11];  const float* b_ln2 = (const float*)d_in[12];
    const float* W_c12 = (const float*)d_in[13];  const float* b_c12 = (const float*)d_in[14];
    const float* W_c22 = (const float*)d_in[15];  const float* b_c22 = (const float*)d_in[16];
    const float* W_ln3 = (const float*)d_in[17];  const float* b_ln3 = (const float*)d_in[18];
    const float* W_c13 = (const float*)d_in[19];  const float* b_c13 = (const float*)d_in[20];
    const float* W_c23 = (const float*)d_in[21];  const float* b_c23 = (const float*)d_in[22];

    const int N = in_sizes[0] / 128;   // 50000
    const int E = in_sizes[2];         // 600000

    // ---- workspace layout ----
    auto align_up = [](size_t v) { return (v + 255) & ~(size_t)255; };
    char* base = (char*)d_ws;
    size_t off = 0;
    auto take = [&](size_t bytes) { char* p = base + off; off += align_up(bytes); return p; };

    float*     xA   = (float*)    take((size_t)N * 128 * 4);
    float*     xB   = (float*)    take((size_t)N * 128 * 4);
    _Float16*  hc   = (_Float16*) take((size_t)2 * N * 128 * 2);   // combined [2N][128]; layer3 aliases [2N][40]

    _Float16* Wt1 = (_Float16*)take((size_t)3 * 2 * 128 * 128 * 2);
    _Float16* Wt2 = (_Float16*)take((size_t)3 * 2 * 128 * 128 * 2);
    _Float16* Wt3 = (_Float16*)take((size_t)3 * 2 * 64 * 128 * 2);

    int*       cnt  = (int*)      take((size_t)N * 4);
    int*       rp   = (int*)      take((size_t)(N + 1) * 4);
    long long* pack = (long long*)take((size_t)2 * E * 8);
    int*       bs   = (int*)      take(256 * 4);

    dim3 blk(256);
    const int gN   = (N + 255) / 256;
    const int gN1  = (N + 1 + 255) / 256;
    const int gE2  = (2 * E + 255) / 256;
    dim3 gg3((N + 63) / 64);
    dim3 gg128((N + 7) / 8);
    dim3 gg40((N + 15) / 16);
    dim3 gls((N + 3) / 4);

    // ---- W preprocessing (3 launches) ----
    wsplit3<<<dim3((128 * 128 + 255) / 256, 3), blk, 0, stream>>>(W_ln1, W_c11, W_c21, Wt1, 128, 128);
    wsplit3<<<dim3((128 * 128 + 255) / 256, 3), blk, 0, stream>>>(W_ln2, W_c12, W_c22, Wt2, 128, 128);
    wsplit3<<<dim3((64 * 128 + 255) / 256, 3), blk, 0, stream>>>(W_ln3, W_c13, W_c23, Wt3, 40, 64);

    // ---- build combined CSR (6 launches) ----
    zero_i32<<<gN, blk, 0, stream>>>(cnt, N);
    hist_c<<<gE2, blk, 0, stream>>>(ei1, ei2, E, cnt);
    scan_phase1<<<gN1, blk, 0, stream>>>(cnt, N, bs, N + 1);
    scan_phase2<<<1, blk, 0, stream>>>(bs, gN1);
    scan_phase3<<<gN1, blk, 0, stream>>>(cnt, N, bs, rp, N + 1);
    fill_direct<<<gE2, blk, 0, stream>>>(ei1, ew1, ei2, ew2, E, N, rp, cnt, pack);

    // ---- Block 1: x -> xA ----
    gemm3<128, 4><<<gg3, blk, 0, stream>>>(x, Wt1, b_ln1, b_c11, b_c21, xA, hc, hc + (size_t)N * 128, 128, N);
    gather_c128<<<gg128, blk, 0, stream>>>(hc, rp, pack, xA, N);

    // ---- Block 2: xA -> xB ----
    gemm3<128, 4><<<gg3, blk, 0, stream>>>(xA, Wt2, b_ln2, b_c12, b_c22, xB, hc, hc + (size_t)N * 128, 128, N);
    gather_c128<<<gg128, blk, 0, stream>>>(hc, rp, pack, xB, N);

    // ---- Block 3: xB -> xA (width 40) ----
    gemm3<64, 2><<<gg3, blk, 0, stream>>>(xB, Wt3, b_ln3, b_c13, b_c23, xA, hc, hc + (size_t)N * 40, 40, N);
    gather_c40<<<gg40, blk, 0, stream>>>(hc, rp, pack, xA, N);

    // ---- log_softmax -> d_out ----
    logsoftmax40<<<gls, blk, 0, stream>>>(xA, (float*)d_out, N);
}

// Round 6
// 427.188 us; speedup vs baseline: 12.0108x; 1.0511x over previous
//
#include <hip/hip_runtime.h>
#include <math.h>

typedef _Float16 f16x8 __attribute__((ext_vector_type(8)));
typedef _Float16 f16x4 __attribute__((ext_vector_type(4)));
typedef float    f32x4 __attribute__((ext_vector_type(4)));

// ---------------- W preprocess: 3 matrices f32 [k][col] -> f16 hi/lo, [col][k] ----------------
__global__ void wsplit3(const float* __restrict__ W0, const float* __restrict__ W1,
                        const float* __restrict__ W2, _Float16* __restrict__ dst,
                        int M, int MPAD)
{
    int b = blockIdx.y;
    const float* W = (b == 0) ? W0 : ((b == 1) ? W1 : W2);
    _Float16* d = dst + (size_t)b * 2 * MPAD * 128;
    int idx = blockIdx.x * 256 + threadIdx.x;
    if (idx >= MPAD * 128) return;
    int col = idx >> 7, k = idx & 127;
    float v = (col < M) ? W[(size_t)k * M + col] : 0.f;
    _Float16 h = (_Float16)v;
    d[(size_t)col * 128 + k] = h;
    d[(size_t)MPAD * 128 + (size_t)col * 128 + k] = (_Float16)(v - (float)h);
}

// ---------------- fused 3-branch GEMM, split-f16 MFMA, W from L2, full-width col tile ----
template<int MPAD, int NN>
__global__ __launch_bounds__(256)
void gemm3(const float* __restrict__ X, const _Float16* __restrict__ Wt,
           const float* __restrict__ b0, const float* __restrict__ b1,
           const float* __restrict__ b2,
           float* __restrict__ out0, _Float16* __restrict__ out1, _Float16* __restrict__ out2,
           int M, int nrows)
{
    constexpr int KP = 136;                       // 128 + 8 f16 pad
    __shared__ _Float16 xh[64][KP], xl[64][KP];

    const int tid  = threadIdx.x;
    const int row0 = blockIdx.x * 64;

    #pragma unroll
    for (int i = 0; i < 8; ++i) {
        int idx = tid + i * 256;
        int row = idx >> 5;
        int k   = (idx & 31) * 4;
        int gr  = row0 + row;
        float4 v = make_float4(0.f, 0.f, 0.f, 0.f);
        if (gr < nrows) v = *(const float4*)(X + (size_t)gr * 128 + k);
        f16x4 h, l;
        float vv[4] = {v.x, v.y, v.z, v.w};
        #pragma unroll
        for (int j = 0; j < 4; ++j) {
            _Float16 hj = (_Float16)vv[j];
            h[j] = hj;
            l[j] = (_Float16)(vv[j] - (float)hj);
        }
        *(f16x4*)&xh[row][k] = h;
        *(f16x4*)&xl[row][k] = l;
    }
    __syncthreads();

    const int lane = tid & 63;
    const int wid  = tid >> 6;
    const int wr   = wid >> 1, wc = wid & 1;
    const int r    = lane & 15, g = lane >> 4;

    f16x8 Ah[2][4], Al[2][4];
    #pragma unroll
    for (int m = 0; m < 2; ++m)
        #pragma unroll
        for (int kk = 0; kk < 4; ++kk) {
            int arow = wr * 32 + m * 16 + r;
            int k0   = kk * 32 + g * 8;
            Ah[m][kk] = *(const f16x8*)&xh[arow][k0];
            Al[m][kk] = *(const f16x8*)&xl[arow][k0];
        }

    #pragma unroll
    for (int br = 0; br < 3; ++br) {
        const _Float16* wbh = Wt + (size_t)br * 2 * MPAD * 128;
        const _Float16* wbl = wbh + (size_t)MPAD * 128;

        f32x4 acc[2][NN];
        #pragma unroll
        for (int m = 0; m < 2; ++m)
            #pragma unroll
            for (int n = 0; n < NN; ++n)
                acc[m][n] = (f32x4){0.f, 0.f, 0.f, 0.f};

        #pragma unroll
        for (int n = 0; n < NN; ++n) {
            int bcol = (n >> 1) * 64 + wc * 32 + (n & 1) * 16 + r;
            #pragma unroll
            for (int kk = 0; kk < 4; ++kk) {
                int k0 = kk * 32 + g * 8;
                f16x8 Bh = *(const f16x8*)&wbh[(size_t)bcol * 128 + k0];
                f16x8 Bl = *(const f16x8*)&wbl[(size_t)bcol * 128 + k0];
                #pragma unroll
                for (int m = 0; m < 2; ++m) {
                    acc[m][n] = __builtin_amdgcn_mfma_f32_16x16x32_f16(Ah[m][kk], Bh, acc[m][n], 0, 0, 0);
                    acc[m][n] = __builtin_amdgcn_mfma_f32_16x16x32_f16(Ah[m][kk], Bl, acc[m][n], 0, 0, 0);
                    acc[m][n] = __builtin_amdgcn_mfma_f32_16x16x32_f16(Al[m][kk], Bh, acc[m][n], 0, 0, 0);
                }
            }
        }

        #pragma unroll
        for (int m = 0; m < 2; ++m)
            #pragma unroll
            for (int n = 0; n < NN; ++n) {
                int col = (n >> 1) * 64 + wc * 32 + (n & 1) * 16 + r;
                if (col >= M) continue;
                if (br == 0) {
                    float bs = b0[col] + b1[col] + b2[col];
                    #pragma unroll
                    for (int i = 0; i < 4; ++i) {
                        int row = row0 + wr * 32 + m * 16 + g * 4 + i;
                        if (row < nrows)
                            out0[(size_t)row * M + col] = acc[m][n][i] + bs;
                    }
                } else {
                    _Float16* outp = (br == 1) ? out1 : out2;
                    #pragma unroll
                    for (int i = 0; i < 4; ++i) {
                        int row = row0 + wr * 32 + m * 16 + g * 4 + i;
                        if (row < nrows)
                            outp[(size_t)row * M + col] = (_Float16)acc[m][n][i];
                    }
                }
            }
    }
}

// ---------------- combined CSR build over both edge sets (2E edges) ----------------
__global__ void zero_i32(int* __restrict__ p, int n)
{
    int i = blockIdx.x * 256 + threadIdx.x;
    if (i < n) p[i] = 0;
}

__global__ void hist_c(const int* __restrict__ ei1, const int* __restrict__ ei2,
                       int E, int* __restrict__ cnt)
{
    int i = blockIdx.x * 256 + threadIdx.x;
    if (i >= 2 * E) return;
    int d = (i < E) ? ei1[E + i] : ei2[E + (i - E)];
    atomicAdd(&cnt[d], 1);
}

__global__ void scan_phase1(const int* __restrict__ cnt, int ncnt, int* __restrict__ bsums, int n)
{
    __shared__ int s[256];
    int tid = threadIdx.x;
    int i = blockIdx.x * 256 + tid;
    int v = (i < n && i < ncnt) ? cnt[i] : 0;
    s[tid] = v; __syncthreads();
    for (int off = 128; off; off >>= 1) {
        if (tid < off) s[tid] += s[tid + off];
        __syncthreads();
    }
    if (tid == 0) bsums[blockIdx.x] = s[0];
}

__global__ void scan_phase2(int* __restrict__ bsums, int nb)
{
    __shared__ int s[256];
    int tid = threadIdx.x;
    int v = (tid < nb) ? bsums[tid] : 0;
    s[tid] = v; __syncthreads();
    for (int off = 1; off < 256; off <<= 1) {
        int t = (tid >= off) ? s[tid - off] : 0;
        __syncthreads();
        s[tid] += t;
        __syncthreads();
    }
    if (tid < nb) bsums[tid] = s[tid] - v;   // exclusive
}

// also zeroes cnt (reused as fill cursor in binplace)
__global__ void scan_phase3(int* __restrict__ cnt, int ncnt,
                            const int* __restrict__ bsums, int* __restrict__ row_ptr, int n)
{
    __shared__ int s[256];
    int tid = threadIdx.x;
    int i = blockIdx.x * 256 + tid;
    int v = (i < n && i < ncnt) ? cnt[i] : 0;
    s[tid] = v; __syncthreads();
    for (int off = 1; off < 256; off <<= 1) {
        int t = (tid >= off) ? s[tid - off] : 0;
        __syncthreads();
        s[tid] += t;
        __syncthreads();
    }
    if (i < n) {
        row_ptr[i] = s[tid] - v + bsums[blockIdx.x];
        if (i < ncnt) cnt[i] = 0;
    }
}

__global__ void init_bincur(const int* __restrict__ rp, int N, int nbins, int* __restrict__ bincur)
{
    int b = blockIdx.x * 256 + threadIdx.x;
    if (b < nbins) {
        int r = b << 9;
        bincur[b] = rp[r < N ? r : N];
    }
}

// ---------------- phase C: bin-bucketed staging of edge records ----------------
// record = {w:f32 | s':u32}; per-slot in-bin row offset (d & 511) stored separately.
constexpr int EPB  = 2048;    // edges per block
constexpr int MAXB = 128;     // max bins (N <= 65536)

__global__ __launch_bounds__(256)
void binfill(const int* __restrict__ ei1, const float* __restrict__ ew1,
             const int* __restrict__ ei2, const float* __restrict__ ew2,
             int E, int N, int nbins, int* __restrict__ bincur,
             long long* __restrict__ stage, unsigned short* __restrict__ soff)
{
    __shared__ int hist[MAXB];
    __shared__ int scanb[MAXB];      // inclusive scan of hist
    __shared__ int gbase[MAXB];
    __shared__ long long srec[EPB];
    __shared__ unsigned short sdo[EPB];      // d & 511
    __shared__ unsigned char  sbin[EPB];

    const int t = threadIdx.x;
    const long long base = (long long)blockIdx.x * EPB;
    int total = 2 * E - (int)base; if (total > EPB) total = EPB;

    for (int i = t; i < MAXB; i += 256) hist[i] = 0;
    __syncthreads();

    int myb[8], myr[8], myo[8];
    long long myrec[8];
    #pragma unroll
    for (int k = 0; k < 8; ++k) {
        int i = t + k * 256;
        myb[k] = -1;
        if (i < total) {
            int j = (int)(base + i);
            int set = (j >= E);
            int e = set ? j - E : j;
            const int* ei = set ? ei2 : ei1;
            int d = ei[E + e];
            int s = ei[e] + (set ? N : 0);
            float w = set ? ew2[e] : ew1[e];
            myb[k] = d >> 9;
            myo[k] = d & 511;
            myrec[k] = ((long long)__float_as_int(w) << 32) | (unsigned)s;
            myr[k] = atomicAdd(&hist[myb[k]], 1);
        }
    }
    __syncthreads();

    // inclusive Hillis-Steele scan over MAXB entries
    if (t < MAXB) scanb[t] = hist[t];
    __syncthreads();
    for (int off = 1; off < MAXB; off <<= 1) {
        int tv = 0;
        if (t < MAXB && t >= off) tv = scanb[t - off];
        __syncthreads();
        if (t < MAXB) scanb[t] += tv;
        __syncthreads();
    }
    // reserve contiguous runs in global bins
    if (t < nbins && hist[t] > 0)
        gbase[t] = atomicAdd(&bincur[t], hist[t]);
    __syncthreads();

    // place into LDS grouped by bin
    #pragma unroll
    for (int k = 0; k < 8; ++k) {
        if (myb[k] >= 0) {
            int slot = scanb[myb[k]] - hist[myb[k]] + myr[k];
            srec[slot] = myrec[k];
            sdo[slot]  = (unsigned short)myo[k];
            sbin[slot] = (unsigned char)myb[k];
        }
    }
    __syncthreads();

    // linear flush: consecutive threads -> consecutive slots -> coalesced runs
    #pragma unroll
    for (int k = 0; k < 8; ++k) {
        int i = t + k * 256;
        if (i < total) {
            int b = sbin[i];
            int addr = gbase[b] + (i - (scanb[b] - hist[b]));
            stage[addr] = srec[i];
            soff[addr]  = sdo[i];
        }
    }
}

// ---------------- phase D: within-bin scatter to final CSR slots (L2-local) ----------------
__global__ __launch_bounds__(256)
void binplace(const long long* __restrict__ stage, const unsigned short* __restrict__ soff,
              const int* __restrict__ rp, int N, int* __restrict__ cur,
              long long* __restrict__ pack)
{
    int bin  = blockIdx.x >> 1;
    int half = blockIdx.x & 1;
    int r0 = bin << 9;
    int r1 = r0 + 512; if (r1 > N) r1 = N;
    if (r0 >= N) return;
    int beg = rp[r0], end = rp[r1];
    int mid = beg + ((end - beg + 1) >> 1);
    int lo = half ? mid : beg;
    int hi = half ? end : mid;
    for (int i = lo + threadIdx.x; i < hi; i += 256) {
        long long rec = stage[i];
        int d = r0 + soff[i];
        int p = rp[d] + atomicAdd(&cur[d], 1);
        pack[p] = rec;
    }
}

// ---------------- combined gather: out[row] += sum_i w_i * hc[src'_i] ----------------
__global__ __launch_bounds__(256)
void gather_c128(const _Float16* __restrict__ hc, const int* __restrict__ rp,
                 const long long* __restrict__ pack, float* __restrict__ out, int N)
{
    int row = blockIdx.x * 8 + (threadIdx.x >> 5);
    if (row >= N) return;
    int lane = threadIdx.x & 31;
    int beg = rp[row], end = rp[row + 1];
    float a0 = 0.f, a1 = 0.f, a2 = 0.f, a3 = 0.f;
    int i = beg;
    for (; i + 2 <= end; i += 2) {
        long long q0 = pack[i], q1 = pack[i + 1];
        int   sa = (int)(unsigned)q0,          sb = (int)(unsigned)q1;
        float wa = __int_as_float((int)(q0 >> 32)), wb = __int_as_float((int)(q1 >> 32));
        f16x4 va = *(const f16x4*)(hc + (size_t)sa * 128 + lane * 4);
        f16x4 vb = *(const f16x4*)(hc + (size_t)sb * 128 + lane * 4);
        a0 = fmaf(wa, (float)va[0], a0); a1 = fmaf(wa, (float)va[1], a1);
        a2 = fmaf(wa, (float)va[2], a2); a3 = fmaf(wa, (float)va[3], a3);
        a0 = fmaf(wb, (float)vb[0], a0); a1 = fmaf(wb, (float)vb[1], a1);
        a2 = fmaf(wb, (float)vb[2], a2); a3 = fmaf(wb, (float)vb[3], a3);
    }
    if (i < end) {
        long long q0 = pack[i];
        int   sa = (int)(unsigned)q0;
        float wa = __int_as_float((int)(q0 >> 32));
        f16x4 va = *(const f16x4*)(hc + (size_t)sa * 128 + lane * 4);
        a0 = fmaf(wa, (float)va[0], a0); a1 = fmaf(wa, (float)va[1], a1);
        a2 = fmaf(wa, (float)va[2], a2); a3 = fmaf(wa, (float)va[3], a3);
    }
    float* o = out + (size_t)row * 128 + lane * 4;
    float4 c = *(float4*)o;
    c.x += a0; c.y += a1; c.z += a2; c.w += a3;
    *(float4*)o = c;
}

__global__ __launch_bounds__(256)
void gather_c40(const _Float16* __restrict__ hc, const int* __restrict__ rp,
                const long long* __restrict__ pack, float* __restrict__ out, int N)
{
    int row = blockIdx.x * 16 + (threadIdx.x >> 4);
    int lane = threadIdx.x & 15;
    if (row >= N || lane >= 10) return;
    int beg = rp[row], end = rp[row + 1];
    float a0 = 0.f, a1 = 0.f, a2 = 0.f, a3 = 0.f;
    int i = beg;
    for (; i + 2 <= end; i += 2) {
        long long q0 = pack[i], q1 = pack[i + 1];
        int   sa = (int)(unsigned)q0,          sb = (int)(unsigned)q1;
        float wa = __int_as_float((int)(q0 >> 32)), wb = __int_as_float((int)(q1 >> 32));
        f16x4 va = *(const f16x4*)(hc + (size_t)sa * 40 + lane * 4);
        f16x4 vb = *(const f16x4*)(hc + (size_t)sb * 40 + lane * 4);
        a0 = fmaf(wa, (float)va[0], a0); a1 = fmaf(wa, (float)va[1], a1);
        a2 = fmaf(wa, (float)va[2], a2); a3 = fmaf(wa, (float)va[3], a3);
        a0 = fmaf(wb, (float)vb[0], a0); a1 = fmaf(wb, (float)vb[1], a1);
        a2 = fmaf(wb, (float)vb[2], a2); a3 = fmaf(wb, (float)vb[3], a3);
    }
    if (i < end) {
        long long q0 = pack[i];
        int   sa = (int)(unsigned)q0;
        float wa = __int_as_float((int)(q0 >> 32));
        f16x4 va = *(const f16x4*)(hc + (size_t)sa * 40 + lane * 4);
        a0 = fmaf(wa, (float)va[0], a0); a1 = fmaf(wa, (float)va[1], a1);
        a2 = fmaf(wa, (float)va[2], a2); a3 = fmaf(wa, (float)va[3], a3);
    }
    float* o = out + (size_t)row * 40 + lane * 4;
    float4 c = *(float4*)o;
    c.x += a0; c.y += a1; c.z += a2; c.w += a3;
    *(float4*)o = c;
}

// ---------------- log_softmax over 40 cols, one wave per row ----------------
__global__ __launch_bounds__(256)
void logsoftmax40(const float* __restrict__ in, float* __restrict__ out, int nrows)
{
    int wave = threadIdx.x >> 6;
    int lane = threadIdx.x & 63;
    int r = blockIdx.x * 4 + wave;
    if (r >= nrows) return;
    float v = (lane < 40) ? in[(size_t)r * 40 + lane] : -INFINITY;
    float m = v;
    #pragma unroll
    for (int off = 32; off; off >>= 1) m = fmaxf(m, __shfl_xor(m, off, 64));
    float e = (lane < 40) ? expf(v - m) : 0.f;
    float s = e;
    #pragma unroll
    for (int off = 32; off; off >>= 1) s += __shfl_xor(s, off, 64);
    if (lane < 40) out[(size_t)r * 40 + lane] = v - m - logf(s);
}

// ---------------- launch ----------------
extern "C" void kernel_launch(void* const* d_in, const int* in_sizes, int n_in,
                              void* d_out, int out_size, void* d_ws, size_t ws_size,
                              hipStream_t stream)
{
    const float* x    = (const float*)d_in[0];
    const int*   ei1  = (const int*)  d_in[1];
    const float* ew1  = (const float*)d_in[2];
    const int*   ei2  = (const int*)  d_in[3];
    const float* ew2  = (const float*)d_in[4];

    const float* W_ln1 = (const float*)d_in[5];   const float* b_ln1 = (const float*)d_in[6];
    const float* W_c11 = (const float*)d_in[7];   const float* b_c11 = (const float*)d_in[8];
    const float* W_c21 = (const float*)d_in[9];   const float* b_c21 = (const float*)d_in[10];
    const float* W_ln2 = (const float*)d_in[11];  const float* b_ln2 = (const float*)d_in[12];
    const float* W_c12 = (const float*)d_in[13];  const float* b_c12 = (const float*)d_in[14];
    const float* W_c22 = (const float*)d_in[15];  const float* b_c22 = (const float*)d_in[16];
    const float* W_ln3 = (const float*)d_in[17];  const float* b_ln3 = (const float*)d_in[18];
    const float* W_c13 = (const float*)d_in[19];  const float* b_c13 = (const float*)d_in[20];
    const float* W_c23 = (const float*)d_in[21];  const float* b_c23 = (const float*)d_in[22];

    const int N = in_sizes[0] / 128;   // 50000
    const int E = in_sizes[2];         // 600000
    const int nbins = (N + 511) >> 9;  // 98

    // ---- workspace layout ----
    auto align_up = [](size_t v) { return (v + 255) & ~(size_t)255; };
    char* base = (char*)d_ws;
    size_t off = 0;
    auto take = [&](size_t bytes) { char* p = base + off; off += align_up(bytes); return p; };

    float*     xA   = (float*)    take((size_t)N * 128 * 4);
    float*     xB   = (float*)    take((size_t)N * 128 * 4);
    _Float16*  hc   = (_Float16*) take((size_t)2 * N * 128 * 2);   // combined [2N][128]; layer3 aliases [2N][40]

    _Float16* Wt1 = (_Float16*)take((size_t)3 * 2 * 128 * 128 * 2);
    _Float16* Wt2 = (_Float16*)take((size_t)3 * 2 * 128 * 128 * 2);
    _Float16* Wt3 = (_Float16*)take((size_t)3 * 2 * 64 * 128 * 2);

    int*       cnt  = (int*)      take((size_t)N * 4);
    int*       rp   = (int*)      take((size_t)(N + 1) * 4);
    long long* pack = (long long*)take((size_t)2 * E * 8);
    int*       bs   = (int*)      take(256 * 4);
    int*       bincur = (int*)    take(MAXB * 4);

    // staging aliases hc (dead until first gemm3): 9.6MB + 2.4MB < 25.6MB
    long long*      stage = (long long*)hc;
    unsigned short* soff  = (unsigned short*)((char*)hc + (size_t)2 * E * 8);

    dim3 blk(256);
    const int gN   = (N + 255) / 256;
    const int gN1  = (N + 1 + 255) / 256;
    const int gE2  = (2 * E + 255) / 256;
    const int gBF  = (2 * E + EPB - 1) / EPB;
    dim3 gg3((N + 63) / 64);
    dim3 gg128((N + 7) / 8);
    dim3 gg40((N + 15) / 16);
    dim3 gls((N + 3) / 4);

    // ---- W preprocessing ----
    wsplit3<<<dim3((128 * 128 + 255) / 256, 3), blk, 0, stream>>>(W_ln1, W_c11, W_c21, Wt1, 128, 128);
    wsplit3<<<dim3((128 * 128 + 255) / 256, 3), blk, 0, stream>>>(W_ln2, W_c12, W_c22, Wt2, 128, 128);
    wsplit3<<<dim3((64 * 128 + 255) / 256, 3), blk, 0, stream>>>(W_ln3, W_c13, W_c23, Wt3, 40, 64);

    // ---- build combined CSR ----
    zero_i32<<<gN, blk, 0, stream>>>(cnt, N);
    hist_c<<<gE2, blk, 0, stream>>>(ei1, ei2, E, cnt);
    scan_phase1<<<gN1, blk, 0, stream>>>(cnt, N, bs, N + 1);
    scan_phase2<<<1, blk, 0, stream>>>(bs, gN1);
    scan_phase3<<<gN1, blk, 0, stream>>>(cnt, N, bs, rp, N + 1);
    init_bincur<<<1, blk, 0, stream>>>(rp, N, nbins, bincur);
    binfill<<<gBF, blk, 0, stream>>>(ei1, ew1, ei2, ew2, E, N, nbins, bincur, stage, soff);
    binplace<<<nbins * 2, blk, 0, stream>>>(stage, soff, rp, N, cnt, pack);

    // ---- Block 1: x -> xA ----
    gemm3<128, 4><<<gg3, blk, 0, stream>>>(x, Wt1, b_ln1, b_c11, b_c21, xA, hc, hc + (size_t)N * 128, 128, N);
    gather_c128<<<gg128, blk, 0, stream>>>(hc, rp, pack, xA, N);

    // ---- Block 2: xA -> xB ----
    gemm3<128, 4><<<gg3, blk, 0, stream>>>(xA, Wt2, b_ln2, b_c12, b_c22, xB, hc, hc + (size_t)N * 128, 128, N);
    gather_c128<<<gg128, blk, 0, stream>>>(hc, rp, pack, xB, N);

    // ---- Block 3: xB -> xA (width 40) ----
    gemm3<64, 2><<<gg3, blk, 0, stream>>>(xB, Wt3, b_ln3, b_c13, b_c23, xA, hc, hc + (size_t)N * 40, 40, N);
    gather_c40<<<gg40, blk, 0, stream>>>(hc, rp, pack, xA, N);

    // ---- log_softmax -> d_out ----
    logsoftmax40<<<gls, blk, 0, stream>>>(xA, (float*)d_out, N);
}

// Round 7
// 420.740 us; speedup vs baseline: 12.1949x; 1.0153x over previous
//
#include <hip/hip_runtime.h>
#include <math.h>

typedef _Float16 f16x8 __attribute__((ext_vector_type(8)));
typedef _Float16 f16x4 __attribute__((ext_vector_type(4)));
typedef float    f32x4 __attribute__((ext_vector_type(4)));

// ---------------- W preprocess: 3 matrices f32 [k][col] -> f16 hi/lo, [col][k] ----------------
__global__ void wsplit3(const float* __restrict__ W0, const float* __restrict__ W1,
                        const float* __restrict__ W2, _Float16* __restrict__ dst,
                        int M, int MPAD)
{
    int b = blockIdx.y;
    const float* W = (b == 0) ? W0 : ((b == 1) ? W1 : W2);
    _Float16* d = dst + (size_t)b * 2 * MPAD * 128;
    int idx = blockIdx.x * 256 + threadIdx.x;
    if (idx >= MPAD * 128) return;
    int col = idx >> 7, k = idx & 127;
    float v = (col < M) ? W[(size_t)k * M + col] : 0.f;
    _Float16 h = (_Float16)v;
    d[(size_t)col * 128 + k] = h;
    d[(size_t)MPAD * 128 + (size_t)col * 128 + k] = (_Float16)(v - (float)h);
}

// ---------------- branch-parallel split-f16 MFMA GEMM ----------------
// grid = (nrows/64, 3 branches); block = 256 threads (2x2 waves, 32-row x M/2-col wave tile).
// branch 0 -> f32 out0 (+ b0+b1+b2); branches 1,2 -> f16 out1/out2.
template<int MPAD, int NN>
__global__ __launch_bounds__(256, 4)
void gemm3(const float* __restrict__ X, const _Float16* __restrict__ Wt,
           const float* __restrict__ b0, const float* __restrict__ b1,
           const float* __restrict__ b2,
           float* __restrict__ out0, _Float16* __restrict__ out1, _Float16* __restrict__ out2,
           int M, int nrows)
{
    constexpr int KP = 136;                       // 128 + 8 f16 pad
    __shared__ _Float16 xh[64][KP], xl[64][KP];

    const int tid  = threadIdx.x;
    const int row0 = blockIdx.x * 64;
    const int br   = blockIdx.y;

    // ---- stage X tile (64 rows x 128 k), split f32 -> f16 hi/lo ----
    #pragma unroll
    for (int i = 0; i < 8; ++i) {
        int idx = tid + i * 256;
        int row = idx >> 5;
        int k   = (idx & 31) * 4;
        int gr  = row0 + row;
        float4 v = make_float4(0.f, 0.f, 0.f, 0.f);
        if (gr < nrows) v = *(const float4*)(X + (size_t)gr * 128 + k);
        f16x4 h, l;
        float vv[4] = {v.x, v.y, v.z, v.w};
        #pragma unroll
        for (int j = 0; j < 4; ++j) {
            _Float16 hj = (_Float16)vv[j];
            h[j] = hj;
            l[j] = (_Float16)(vv[j] - (float)hj);
        }
        *(f16x4*)&xh[row][k] = h;
        *(f16x4*)&xl[row][k] = l;
    }
    __syncthreads();

    const int lane = tid & 63;
    const int wid  = tid >> 6;
    const int wr   = wid >> 1, wc = wid & 1;
    const int r    = lane & 15, g = lane >> 4;

    const _Float16* wbh = Wt + (size_t)br * 2 * MPAD * 128;
    const _Float16* wbl = wbh + (size_t)MPAD * 128;

    f32x4 acc[2][NN];
    #pragma unroll
    for (int m = 0; m < 2; ++m)
        #pragma unroll
        for (int n = 0; n < NN; ++n)
            acc[m][n] = (f32x4){0.f, 0.f, 0.f, 0.f};

    #pragma unroll
    for (int n = 0; n < NN; ++n) {
        int bcol = (n >> 1) * 64 + wc * 32 + (n & 1) * 16 + r;
        #pragma unroll
        for (int kk = 0; kk < 4; ++kk) {
            int k0 = kk * 32 + g * 8;
            f16x8 Bh = *(const f16x8*)&wbh[(size_t)bcol * 128 + k0];
            f16x8 Bl = *(const f16x8*)&wbl[(size_t)bcol * 128 + k0];
            #pragma unroll
            for (int m = 0; m < 2; ++m) {
                int arow = wr * 32 + m * 16 + r;
                f16x8 Ah = *(const f16x8*)&xh[arow][k0];
                f16x8 Al = *(const f16x8*)&xl[arow][k0];
                acc[m][n] = __builtin_amdgcn_mfma_f32_16x16x32_f16(Ah, Bh, acc[m][n], 0, 0, 0);
                acc[m][n] = __builtin_amdgcn_mfma_f32_16x16x32_f16(Ah, Bl, acc[m][n], 0, 0, 0);
                acc[m][n] = __builtin_amdgcn_mfma_f32_16x16x32_f16(Al, Bh, acc[m][n], 0, 0, 0);
            }
        }
    }

    #pragma unroll
    for (int m = 0; m < 2; ++m)
        #pragma unroll
        for (int n = 0; n < NN; ++n) {
            int col = (n >> 1) * 64 + wc * 32 + (n & 1) * 16 + r;
            if (col >= M) continue;
            if (br == 0) {
                float bs = b0[col] + b1[col] + b2[col];
                #pragma unroll
                for (int i = 0; i < 4; ++i) {
                    int row = row0 + wr * 32 + m * 16 + g * 4 + i;
                    if (row < nrows)
                        out0[(size_t)row * M + col] = acc[m][n][i] + bs;
                }
            } else {
                _Float16* outp = (br == 1) ? out1 : out2;
                #pragma unroll
                for (int i = 0; i < 4; ++i) {
                    int row = row0 + wr * 32 + m * 16 + g * 4 + i;
                    if (row < nrows)
                        outp[(size_t)row * M + col] = (_Float16)acc[m][n][i];
                }
            }
        }
}

// ---------------- combined CSR build over both edge sets (2E edges) ----------------
__global__ void zero_i32(int* __restrict__ p, int n)
{
    int i = blockIdx.x * 256 + threadIdx.x;
    if (i < n) p[i] = 0;
}

__global__ void hist_c(const int* __restrict__ ei1, const int* __restrict__ ei2,
                       int E, int* __restrict__ cnt)
{
    int i = blockIdx.x * 256 + threadIdx.x;
    if (i >= 2 * E) return;
    int d = (i < E) ? ei1[E + i] : ei2[E + (i - E)];
    atomicAdd(&cnt[d], 1);
}

__global__ void scan_phase1(const int* __restrict__ cnt, int ncnt, int* __restrict__ bsums, int n)
{
    __shared__ int s[256];
    int tid = threadIdx.x;
    int i = blockIdx.x * 256 + tid;
    int v = (i < n && i < ncnt) ? cnt[i] : 0;
    s[tid] = v; __syncthreads();
    for (int off = 128; off; off >>= 1) {
        if (tid < off) s[tid] += s[tid + off];
        __syncthreads();
    }
    if (tid == 0) bsums[blockIdx.x] = s[0];
}

__global__ void scan_phase2(int* __restrict__ bsums, int nb)
{
    __shared__ int s[256];
    int tid = threadIdx.x;
    int v = (tid < nb) ? bsums[tid] : 0;
    s[tid] = v; __syncthreads();
    for (int off = 1; off < 256; off <<= 1) {
        int t = (tid >= off) ? s[tid - off] : 0;
        __syncthreads();
        s[tid] += t;
        __syncthreads();
    }
    if (tid < nb) bsums[tid] = s[tid] - v;   // exclusive
}

// also zeroes cnt (reused as fill cursor in binplace)
__global__ void scan_phase3(int* __restrict__ cnt, int ncnt,
                            const int* __restrict__ bsums, int* __restrict__ row_ptr, int n)
{
    __shared__ int s[256];
    int tid = threadIdx.x;
    int i = blockIdx.x * 256 + tid;
    int v = (i < n && i < ncnt) ? cnt[i] : 0;
    s[tid] = v; __syncthreads();
    for (int off = 1; off < 256; off <<= 1) {
        int t = (tid >= off) ? s[tid - off] : 0;
        __syncthreads();
        s[tid] += t;
        __syncthreads();
    }
    if (i < n) {
        row_ptr[i] = s[tid] - v + bsums[blockIdx.x];
        if (i < ncnt) cnt[i] = 0;
    }
}

__global__ void init_bincur(const int* __restrict__ rp, int N, int nbins, int* __restrict__ bincur)
{
    int b = blockIdx.x * 256 + threadIdx.x;
    if (b < nbins) {
        int r = b << 9;
        bincur[b] = rp[r < N ? r : N];
    }
}

// ---------------- phase C: bin-bucketed staging of edge records ----------------
constexpr int EPB  = 2048;    // edges per block
constexpr int MAXB = 128;     // max bins (N <= 65536)

__global__ __launch_bounds__(256)
void binfill(const int* __restrict__ ei1, const float* __restrict__ ew1,
             const int* __restrict__ ei2, const float* __restrict__ ew2,
             int E, int N, int nbins, int* __restrict__ bincur,
             long long* __restrict__ stage, unsigned short* __restrict__ soff)
{
    __shared__ int hist[MAXB];
    __shared__ int scanb[MAXB];
    __shared__ int gbase[MAXB];
    __shared__ long long srec[EPB];
    __shared__ unsigned short sdo[EPB];
    __shared__ unsigned char  sbin[EPB];

    const int t = threadIdx.x;
    const long long base = (long long)blockIdx.x * EPB;
    int total = 2 * E - (int)base; if (total > EPB) total = EPB;

    for (int i = t; i < MAXB; i += 256) hist[i] = 0;
    __syncthreads();

    int myb[8], myr[8], myo[8];
    long long myrec[8];
    #pragma unroll
    for (int k = 0; k < 8; ++k) {
        int i = t + k * 256;
        myb[k] = -1;
        if (i < total) {
            int j = (int)(base + i);
            int set = (j >= E);
            int e = set ? j - E : j;
            const int* ei = set ? ei2 : ei1;
            int d = ei[E + e];
            int s = ei[e] + (set ? N : 0);
            float w = set ? ew2[e] : ew1[e];
            myb[k] = d >> 9;
            myo[k] = d & 511;
            myrec[k] = ((long long)__float_as_int(w) << 32) | (unsigned)s;
            myr[k] = atomicAdd(&hist[myb[k]], 1);
        }
    }
    __syncthreads();

    if (t < MAXB) scanb[t] = hist[t];
    __syncthreads();
    for (int off = 1; off < MAXB; off <<= 1) {
        int tv = 0;
        if (t < MAXB && t >= off) tv = scanb[t - off];
        __syncthreads();
        if (t < MAXB) scanb[t] += tv;
        __syncthreads();
    }
    if (t < nbins && hist[t] > 0)
        gbase[t] = atomicAdd(&bincur[t], hist[t]);
    __syncthreads();

    #pragma unroll
    for (int k = 0; k < 8; ++k) {
        if (myb[k] >= 0) {
            int slot = scanb[myb[k]] - hist[myb[k]] + myr[k];
            srec[slot] = myrec[k];
            sdo[slot]  = (unsigned short)myo[k];
            sbin[slot] = (unsigned char)myb[k];
        }
    }
    __syncthreads();

    #pragma unroll
    for (int k = 0; k < 8; ++k) {
        int i = t + k * 256;
        if (i < total) {
            int b = sbin[i];
            int addr = gbase[b] + (i - (scanb[b] - hist[b]));
            stage[addr] = srec[i];
            soff[addr]  = sdo[i];
        }
    }
}

// ---------------- phase D: within-bin scatter to final CSR slots (L2-local) ----------------
__global__ __launch_bounds__(256)
void binplace(const long long* __restrict__ stage, const unsigned short* __restrict__ soff,
              const int* __restrict__ rp, int N, int* __restrict__ cur,
              long long* __restrict__ pack)
{
    int bin  = blockIdx.x >> 1;
    int half = blockIdx.x & 1;
    int r0 = bin << 9;
    int r1 = r0 + 512; if (r1 > N) r1 = N;
    if (r0 >= N) return;
    int beg = rp[r0], end = rp[r1];
    int mid = beg + ((end - beg + 1) >> 1);
    int lo = half ? mid : beg;
    int hi = half ? end : mid;
    for (int i = lo + threadIdx.x; i < hi; i += 256) {
        long long rec = stage[i];
        int d = r0 + soff[i];
        int p = rp[d] + atomicAdd(&cur[d], 1);
        pack[p] = rec;
    }
}

// ---------------- combined gather (width 128): out[row] += sum_i w_i * hc[src'_i] ----------------
__global__ __launch_bounds__(256)
void gather_c128(const _Float16* __restrict__ hc, const int* __restrict__ rp,
                 const long long* __restrict__ pack, float* __restrict__ out, int N)
{
    int row = blockIdx.x * 8 + (threadIdx.x >> 5);
    if (row >= N) return;
    int lane = threadIdx.x & 31;
    int beg = rp[row], end = rp[row + 1];
    float a0 = 0.f, a1 = 0.f, a2 = 0.f, a3 = 0.f;
    int i = beg;
    for (; i + 2 <= end; i += 2) {
        long long q0 = pack[i], q1 = pack[i + 1];
        int   sa = (int)(unsigned)q0,          sb = (int)(unsigned)q1;
        float wa = __int_as_float((int)(q0 >> 32)), wb = __int_as_float((int)(q1 >> 32));
        f16x4 va = *(const f16x4*)(hc + (size_t)sa * 128 + lane * 4);
        f16x4 vb = *(const f16x4*)(hc + (size_t)sb * 128 + lane * 4);
        a0 = fmaf(wa, (float)va[0], a0); a1 = fmaf(wa, (float)va[1], a1);
        a2 = fmaf(wa, (float)va[2], a2); a3 = fmaf(wa, (float)va[3], a3);
        a0 = fmaf(wb, (float)vb[0], a0); a1 = fmaf(wb, (float)vb[1], a1);
        a2 = fmaf(wb, (float)vb[2], a2); a3 = fmaf(wb, (float)vb[3], a3);
    }
    if (i < end) {
        long long q0 = pack[i];
        int   sa = (int)(unsigned)q0;
        float wa = __int_as_float((int)(q0 >> 32));
        f16x4 va = *(const f16x4*)(hc + (size_t)sa * 128 + lane * 4);
        a0 = fmaf(wa, (float)va[0], a0); a1 = fmaf(wa, (float)va[1], a1);
        a2 = fmaf(wa, (float)va[2], a2); a3 = fmaf(wa, (float)va[3], a3);
    }
    float* o = out + (size_t)row * 128 + lane * 4;
    float4 c = *(float4*)o;
    c.x += a0; c.y += a1; c.z += a2; c.w += a3;
    *(float4*)o = c;
}

// ---------------- final: gather (width 40) + log_softmax fused, writes d_out ----------------
__global__ __launch_bounds__(256)
void gather_ls40(const _Float16* __restrict__ hc, const int* __restrict__ rp,
                 const long long* __restrict__ pack, const float* __restrict__ xlin,
                 float* __restrict__ out, int N)
{
    int row = blockIdx.x * 16 + (threadIdx.x >> 4);
    int lane = threadIdx.x & 15;
    if (row >= N) return;                      // whole 16-lane group exits together
    bool act = (lane < 10);

    float v0 = -INFINITY, v1 = -INFINITY, v2 = -INFINITY, v3 = -INFINITY;
    if (act) {
        float a0 = 0.f, a1 = 0.f, a2 = 0.f, a3 = 0.f;
        int beg = rp[row], end = rp[row + 1];
        int i = beg;
        for (; i + 2 <= end; i += 2) {
            long long q0 = pack[i], q1 = pack[i + 1];
            int   sa = (int)(unsigned)q0,          sb = (int)(unsigned)q1;
            float wa = __int_as_float((int)(q0 >> 32)), wb = __int_as_float((int)(q1 >> 32));
            f16x4 va = *(const f16x4*)(hc + (size_t)sa * 40 + lane * 4);
            f16x4 vb = *(const f16x4*)(hc + (size_t)sb * 40 + lane * 4);
            a0 = fmaf(wa, (float)va[0], a0); a1 = fmaf(wa, (float)va[1], a1);
            a2 = fmaf(wa, (float)va[2], a2); a3 = fmaf(wa, (float)va[3], a3);
            a0 = fmaf(wb, (float)vb[0], a0); a1 = fmaf(wb, (float)vb[1], a1);
            a2 = fmaf(wb, (float)vb[2], a2); a3 = fmaf(wb, (float)vb[3], a3);
        }
        if (i < end) {
            long long q0 = pack[i];
            int   sa = (int)(unsigned)q0;
            float wa = __int_as_float((int)(q0 >> 32));
            f16x4 va = *(const f16x4*)(hc + (size_t)sa * 40 + lane * 4);
            a0 = fmaf(wa, (float)va[0], a0); a1 = fmaf(wa, (float)va[1], a1);
            a2 = fmaf(wa, (float)va[2], a2); a3 = fmaf(wa, (float)va[3], a3);
        }
        float4 c = *(const float4*)(xlin + (size_t)row * 40 + lane * 4);
        v0 = c.x + a0; v1 = c.y + a1; v2 = c.z + a2; v3 = c.w + a3;
    }

    // max over the 40 values (width-16 butterfly within the group)
    float m = fmaxf(fmaxf(v0, v1), fmaxf(v2, v3));
    #pragma unroll
    for (int off = 8; off; off >>= 1) m = fmaxf(m, __shfl_xor(m, off, 16));
    // sum of exp
    float s = 0.f;
    if (act) s = expf(v0 - m) + expf(v1 - m) + expf(v2 - m) + expf(v3 - m);
    #pragma unroll
    for (int off = 8; off; off >>= 1) s += __shfl_xor(s, off, 16);
    float ls = m + logf(s);

    if (act) {
        float* o = out + (size_t)row * 40 + lane * 4;
        o[0] = v0 - ls; o[1] = v1 - ls; o[2] = v2 - ls; o[3] = v3 - ls;
    }
}

// ---------------- launch ----------------
extern "C" void kernel_launch(void* const* d_in, const int* in_sizes, int n_in,
                              void* d_out, int out_size, void* d_ws, size_t ws_size,
                              hipStream_t stream)
{
    const float* x    = (const float*)d_in[0];
    const int*   ei1  = (const int*)  d_in[1];
    const float* ew1  = (const float*)d_in[2];
    const int*   ei2  = (const int*)  d_in[3];
    const float* ew2  = (const float*)d_in[4];

    const float* W_ln1 = (const float*)d_in[5];   const float* b_ln1 = (const float*)d_in[6];
    const float* W_c11 = (const float*)d_in[7];   const float* b_c11 = (const float*)d_in[8];
    const float* W_c21 = (const float*)d_in[9];   const float* b_c21 = (const float*)d_in[10];
    const float* W_ln2 = (const float*)d_in[11];  const float* b_ln2 = (const float*)d_in[12];
    const float* W_c12 = (const float*)d_in[13];  const float* b_c12 = (const float*)d_in[14];
    const float* W_c22 = (const float*)d_in[15];  const float* b_c22 = (const float*)d_in[16];
    const float* W_ln3 = (const float*)d_in[17];  const float* b_ln3 = (const float*)d_in[18];
    const float* W_c13 = (const float*)d_in[19];  const float* b_c13 = (const float*)d_in[20];
    const float* W_c23 = (const float*)d_in[21];  const float* b_c23 = (const float*)d_in[22];

    const int N = in_sizes[0] / 128;   // 50000
    const int E = in_sizes[2];         // 600000
    const int nbins = (N + 511) >> 9;  // 98

    // ---- workspace layout ----
    auto align_up = [](size_t v) { return (v + 255) & ~(size_t)255; };
    char* base = (char*)d_ws;
    size_t off = 0;
    auto take = [&](size_t bytes) { char* p = base + off; off += align_up(bytes); return p; };

    float*     xA   = (float*)    take((size_t)N * 128 * 4);
    float*     xB   = (float*)    take((size_t)N * 128 * 4);
    _Float16*  hc   = (_Float16*) take((size_t)2 * N * 128 * 2);   // combined [2N][128]; layer3 aliases [2N][40]

    _Float16* Wt1 = (_Float16*)take((size_t)3 * 2 * 128 * 128 * 2);
    _Float16* Wt2 = (_Float16*)take((size_t)3 * 2 * 128 * 128 * 2);
    _Float16* Wt3 = (_Float16*)take((size_t)3 * 2 * 64 * 128 * 2);

    int*       cnt  = (int*)      take((size_t)N * 4);
    int*       rp   = (int*)      take((size_t)(N + 1) * 4);
    long long* pack = (long long*)take((size_t)2 * E * 8);
    int*       bs   = (int*)      take(256 * 4);
    int*       bincur = (int*)    take(MAXB * 4);

    // staging aliases hc (dead until first gemm3)
    long long*      stage = (long long*)hc;
    unsigned short* soff  = (unsigned short*)((char*)hc + (size_t)2 * E * 8);

    dim3 blk(256);
    const int gN   = (N + 255) / 256;
    const int gN1  = (N + 1 + 255) / 256;
    const int gE2  = (2 * E + 255) / 256;
    const int gBF  = (2 * E + EPB - 1) / EPB;
    dim3 gg3((N + 63) / 64, 3);
    dim3 gg128((N + 7) / 8);
    dim3 gg40((N + 15) / 16);

    // ---- W preprocessing ----
    wsplit3<<<dim3((128 * 128 + 255) / 256, 3), blk, 0, stream>>>(W_ln1, W_c11, W_c21, Wt1, 128, 128);
    wsplit3<<<dim3((128 * 128 + 255) / 256, 3), blk, 0, stream>>>(W_ln2, W_c12, W_c22, Wt2, 128, 128);
    wsplit3<<<dim3((64 * 128 + 255) / 256, 3), blk, 0, stream>>>(W_ln3, W_c13, W_c23, Wt3, 40, 64);

    // ---- build combined CSR ----
    zero_i32<<<gN, blk, 0, stream>>>(cnt, N);
    hist_c<<<gE2, blk, 0, stream>>>(ei1, ei2, E, cnt);
    scan_phase1<<<gN1, blk, 0, stream>>>(cnt, N, bs, N + 1);
    scan_phase2<<<1, blk, 0, stream>>>(bs, gN1);
    scan_phase3<<<gN1, blk, 0, stream>>>(cnt, N, bs, rp, N + 1);
    init_bincur<<<1, blk, 0, stream>>>(rp, N, nbins, bincur);
    binfill<<<gBF, blk, 0, stream>>>(ei1, ew1, ei2, ew2, E, N, nbins, bincur, stage, soff);
    binplace<<<nbins * 2, blk, 0, stream>>>(stage, soff, rp, N, cnt, pack);

    // ---- Block 1: x -> xA ----
    gemm3<128, 4><<<gg3, blk, 0, stream>>>(x, Wt1, b_ln1, b_c11, b_c21, xA, hc, hc + (size_t)N * 128, 128, N);
    gather_c128<<<gg128, blk, 0, stream>>>(hc, rp, pack, xA, N);

    // ---- Block 2: xA -> xB ----
    gemm3<128, 4><<<gg3, blk, 0, stream>>>(xA, Wt2, b_ln2, b_c12, b_c22, xB, hc, hc + (size_t)N * 128, 128, N);
    gather_c128<<<gg128, blk, 0, stream>>>(hc, rp, pack, xB, N);

    // ---- Block 3: xB -> xA (width 40), then fused gather+log_softmax -> d_out ----
    gemm3<64, 2><<<gg3, blk, 0, stream>>>(xB, Wt3, b_ln3, b_c13, b_c23, xA, hc, hc + (size_t)N * 40, 40, N);
    gather_ls40<<<gg40, blk, 0, stream>>>(hc, rp, pack, xA, (float*)d_out, N);
}

// Round 8
// 364.703 us; speedup vs baseline: 14.0686x; 1.1537x over previous
//
#include <hip/hip_runtime.h>
#include <math.h>

typedef _Float16 f16x8 __attribute__((ext_vector_type(8)));
typedef _Float16 f16x4 __attribute__((ext_vector_type(4)));
typedef float    f32x4 __attribute__((ext_vector_type(4)));

// XOR-swizzled index into a [rows][128] f16 LDS tile (256B rows, no pad).
// Bank-spread: 16 consecutive rows at the same k land on >=8 distinct bank-quads (2-way max).
__device__ __forceinline__ int swz(int row, int k)
{
    return row * 128 + (k ^ ((row & 15) << 3));
}

// ---------------- W preprocess: 3 matrices f32 [k][col] -> f16 hi/lo, [col][k] ----------------
__global__ void wsplit3(const float* __restrict__ W0, const float* __restrict__ W1,
                        const float* __restrict__ W2, _Float16* __restrict__ dst,
                        int M, int MPAD)
{
    int b = blockIdx.y;
    const float* W = (b == 0) ? W0 : ((b == 1) ? W1 : W2);
    _Float16* d = dst + (size_t)b * 2 * MPAD * 128;
    int idx = blockIdx.x * 256 + threadIdx.x;
    if (idx >= MPAD * 128) return;
    int col = idx >> 7, k = idx & 127;
    float v = (col < M) ? W[(size_t)k * M + col] : 0.f;
    _Float16 h = (_Float16)v;
    d[(size_t)col * 128 + k] = h;
    d[(size_t)MPAD * 128 + (size_t)col * 128 + k] = (_Float16)(v - (float)h);
}

// ---------------- split-f16 MFMA GEMM, W & X in swizzled LDS, 1 barrier ----------------
// grid = (row_tiles, 3 branches, col_halves); block 256 = 2x2 waves, 32row x 32col wave tile.
// branch 0 -> f32 out0 (+ b0+b1+b2); branches 1,2 -> f16 out1/out2.
template<int MPAD>
__global__ __launch_bounds__(256)
void gemm3(const float* __restrict__ X, const _Float16* __restrict__ Wt,
           const float* __restrict__ b0, const float* __restrict__ b1,
           const float* __restrict__ b2,
           float* __restrict__ out0, _Float16* __restrict__ out1, _Float16* __restrict__ out2,
           int M, int nrows)
{
    __shared__ _Float16 xh[64 * 128], xl[64 * 128];   // 32 KB
    __shared__ _Float16 wh[64 * 128], wl[64 * 128];   // 32 KB

    const int tid  = threadIdx.x;
    const int row0 = blockIdx.x * 64;
    const int br   = blockIdx.y;
    const int col0 = blockIdx.z * 64;

    const _Float16* wbh = Wt + (size_t)br * 2 * MPAD * 128 + (size_t)col0 * 128;
    const _Float16* wbl = wbh + (size_t)MPAD * 128;

    // ---- issue W loads (coalesced, L2-hot) ----
    f16x8 wrh[4], wrl[4];
    #pragma unroll
    for (int i = 0; i < 4; ++i) {
        int idx = tid + i * 256;              // 0..1023
        int cl  = idx >> 4;
        int kc  = (idx & 15) * 8;
        wrh[i] = *(const f16x8*)&wbh[cl * 128 + kc];
        wrl[i] = *(const f16x8*)&wbl[cl * 128 + kc];
    }
    // ---- issue X loads (coalesced) ----
    float4 xr[8];
    #pragma unroll
    for (int i = 0; i < 8; ++i) {
        int idx = tid + i * 256;              // 0..2047
        int row = idx >> 5;
        int k   = (idx & 31) * 4;
        int gr  = row0 + row;
        xr[i] = (gr < nrows) ? *(const float4*)(X + (size_t)gr * 128 + k)
                             : make_float4(0.f, 0.f, 0.f, 0.f);
    }
    // ---- split X -> swizzled LDS ----
    #pragma unroll
    for (int i = 0; i < 8; ++i) {
        int idx = tid + i * 256;
        int row = idx >> 5;
        int k   = (idx & 31) * 4;
        float vv[4] = {xr[i].x, xr[i].y, xr[i].z, xr[i].w};
        f16x4 h, l;
        #pragma unroll
        for (int j = 0; j < 4; ++j) {
            _Float16 hj = (_Float16)vv[j];
            h[j] = hj;
            l[j] = (_Float16)(vv[j] - (float)hj);
        }
        int o = swz(row, k);
        *(f16x4*)&xh[o] = h;
        *(f16x4*)&xl[o] = l;
    }
    // ---- W -> swizzled LDS ----
    #pragma unroll
    for (int i = 0; i < 4; ++i) {
        int idx = tid + i * 256;
        int cl  = idx >> 4;
        int kc  = (idx & 15) * 8;
        int o = swz(cl, kc);
        *(f16x8*)&wh[o] = wrh[i];
        *(f16x8*)&wl[o] = wrl[i];
    }
    __syncthreads();

    const int lane = tid & 63;
    const int wid  = tid >> 6;
    const int wr   = wid >> 1, wc = wid & 1;
    const int r    = lane & 15, g = lane >> 4;

    // ---- hoist A fragments ----
    f16x8 Ah[2][4], Al[2][4];
    #pragma unroll
    for (int m = 0; m < 2; ++m)
        #pragma unroll
        for (int kk = 0; kk < 4; ++kk) {
            int o = swz(wr * 32 + m * 16 + r, kk * 32 + g * 8);
            Ah[m][kk] = *(const f16x8*)&xh[o];
            Al[m][kk] = *(const f16x8*)&xl[o];
        }

    f32x4 acc[2][2];
    #pragma unroll
    for (int m = 0; m < 2; ++m)
        #pragma unroll
        for (int n = 0; n < 2; ++n)
            acc[m][n] = (f32x4){0.f, 0.f, 0.f, 0.f};

    #pragma unroll
    for (int n = 0; n < 2; ++n) {
        int bcol = wc * 32 + n * 16 + r;
        #pragma unroll
        for (int kk = 0; kk < 4; ++kk) {
            int o = swz(bcol, kk * 32 + g * 8);
            f16x8 Bh = *(const f16x8*)&wh[o];
            f16x8 Bl = *(const f16x8*)&wl[o];
            #pragma unroll
            for (int m = 0; m < 2; ++m) {
                acc[m][n] = __builtin_amdgcn_mfma_f32_16x16x32_f16(Ah[m][kk], Bh, acc[m][n], 0, 0, 0);
                acc[m][n] = __builtin_amdgcn_mfma_f32_16x16x32_f16(Ah[m][kk], Bl, acc[m][n], 0, 0, 0);
                acc[m][n] = __builtin_amdgcn_mfma_f32_16x16x32_f16(Al[m][kk], Bh, acc[m][n], 0, 0, 0);
            }
        }
    }

    #pragma unroll
    for (int m = 0; m < 2; ++m)
        #pragma unroll
        for (int n = 0; n < 2; ++n) {
            int col = col0 + wc * 32 + n * 16 + r;
            if (col >= M) continue;
            if (br == 0) {
                float bs = b0[col] + b1[col] + b2[col];
                #pragma unroll
                for (int i = 0; i < 4; ++i) {
                    int row = row0 + wr * 32 + m * 16 + g * 4 + i;
                    if (row < nrows)
                        out0[(size_t)row * M + col] = acc[m][n][i] + bs;
                }
            } else {
                _Float16* outp = (br == 1) ? out1 : out2;
                #pragma unroll
                for (int i = 0; i < 4; ++i) {
                    int row = row0 + wr * 32 + m * 16 + g * 4 + i;
                    if (row < nrows)
                        outp[(size_t)row * M + col] = (_Float16)acc[m][n][i];
                }
            }
        }
}

// ---------------- combined CSR build over both edge sets (2E edges) ----------------
__global__ void zero_i32(int* __restrict__ p, int n)
{
    int i = blockIdx.x * 256 + threadIdx.x;
    if (i < n) p[i] = 0;
}

__global__ void hist_c(const int* __restrict__ ei1, const int* __restrict__ ei2,
                       int E, int* __restrict__ cnt)
{
    int i = blockIdx.x * 256 + threadIdx.x;
    if (i >= 2 * E) return;
    int d = (i < E) ? ei1[E + i] : ei2[E + (i - E)];
    atomicAdd(&cnt[d], 1);
}

__global__ void scan_phase1(const int* __restrict__ cnt, int ncnt, int* __restrict__ bsums, int n)
{
    __shared__ int s[256];
    int tid = threadIdx.x;
    int i = blockIdx.x * 256 + tid;
    int v = (i < n && i < ncnt) ? cnt[i] : 0;
    s[tid] = v; __syncthreads();
    for (int off = 128; off; off >>= 1) {
        if (tid < off) s[tid] += s[tid + off];
        __syncthreads();
    }
    if (tid == 0) bsums[blockIdx.x] = s[0];
}

__global__ void scan_phase2(int* __restrict__ bsums, int nb)
{
    __shared__ int s[256];
    int tid = threadIdx.x;
    int v = (tid < nb) ? bsums[tid] : 0;
    s[tid] = v; __syncthreads();
    for (int off = 1; off < 256; off <<= 1) {
        int t = (tid >= off) ? s[tid - off] : 0;
        __syncthreads();
        s[tid] += t;
        __syncthreads();
    }
    if (tid < nb) bsums[tid] = s[tid] - v;   // exclusive
}

// also zeroes cnt (reused as fill cursor in binplace)
__global__ void scan_phase3(int* __restrict__ cnt, int ncnt,
                            const int* __restrict__ bsums, int* __restrict__ row_ptr, int n)
{
    __shared__ int s[256];
    int tid = threadIdx.x;
    int i = blockIdx.x * 256 + tid;
    int v = (i < n && i < ncnt) ? cnt[i] : 0;
    s[tid] = v; __syncthreads();
    for (int off = 1; off < 256; off <<= 1) {
        int t = (tid >= off) ? s[tid - off] : 0;
        __syncthreads();
        s[tid] += t;
        __syncthreads();
    }
    if (i < n) {
        row_ptr[i] = s[tid] - v + bsums[blockIdx.x];
        if (i < ncnt) cnt[i] = 0;
    }
}

__global__ void init_bincur(const int* __restrict__ rp, int N, int nbins, int* __restrict__ bincur)
{
    int b = blockIdx.x * 256 + threadIdx.x;
    if (b < nbins) {
        int r = b << 9;
        bincur[b] = rp[r < N ? r : N];
    }
}

// ---------------- phase C: bin-bucketed staging of edge records ----------------
constexpr int EPB  = 2048;    // edges per block
constexpr int MAXB = 128;     // max bins (N <= 65536)

__global__ __launch_bounds__(256)
void binfill(const int* __restrict__ ei1, const float* __restrict__ ew1,
             const int* __restrict__ ei2, const float* __restrict__ ew2,
             int E, int N, int nbins, int* __restrict__ bincur,
             long long* __restrict__ stage, unsigned short* __restrict__ soff)
{
    __shared__ int hist[MAXB];
    __shared__ int scanb[MAXB];
    __shared__ int gbase[MAXB];
    __shared__ long long srec[EPB];
    __shared__ unsigned short sdo[EPB];
    __shared__ unsigned char  sbin[EPB];

    const int t = threadIdx.x;
    const long long base = (long long)blockIdx.x * EPB;
    int total = 2 * E - (int)base; if (total > EPB) total = EPB;

    for (int i = t; i < MAXB; i += 256) hist[i] = 0;
    __syncthreads();

    int myb[8], myr[8], myo[8];
    long long myrec[8];
    #pragma unroll
    for (int k = 0; k < 8; ++k) {
        int i = t + k * 256;
        myb[k] = -1;
        if (i < total) {
            int j = (int)(base + i);
            int set = (j >= E);
            int e = set ? j - E : j;
            const int* ei = set ? ei2 : ei1;
            int d = ei[E + e];
            int s = ei[e] + (set ? N : 0);
            float w = set ? ew2[e] : ew1[e];
            myb[k] = d >> 9;
            myo[k] = d & 511;
            myrec[k] = ((long long)__float_as_int(w) << 32) | (unsigned)s;
            myr[k] = atomicAdd(&hist[myb[k]], 1);
        }
    }
    __syncthreads();

    if (t < MAXB) scanb[t] = hist[t];
    __syncthreads();
    for (int off = 1; off < MAXB; off <<= 1) {
        int tv = 0;
        if (t < MAXB && t >= off) tv = scanb[t - off];
        __syncthreads();
        if (t < MAXB) scanb[t] += tv;
        __syncthreads();
    }
    if (t < nbins && hist[t] > 0)
        gbase[t] = atomicAdd(&bincur[t], hist[t]);
    __syncthreads();

    #pragma unroll
    for (int k = 0; k < 8; ++k) {
        if (myb[k] >= 0) {
            int slot = scanb[myb[k]] - hist[myb[k]] + myr[k];
            srec[slot] = myrec[k];
            sdo[slot]  = (unsigned short)myo[k];
            sbin[slot] = (unsigned char)myb[k];
        }
    }
    __syncthreads();

    #pragma unroll
    for (int k = 0; k < 8; ++k) {
        int i = t + k * 256;
        if (i < total) {
            int b = sbin[i];
            int addr = gbase[b] + (i - (scanb[b] - hist[b]));
            stage[addr] = srec[i];
            soff[addr]  = sdo[i];
        }
    }
}

// ---------------- phase D: within-bin scatter to final CSR slots (L2-local) ----------------
__global__ __launch_bounds__(256)
void binplace(const long long* __restrict__ stage, const unsigned short* __restrict__ soff,
              const int* __restrict__ rp, int N, int* __restrict__ cur,
              long long* __restrict__ pack)
{
    int bin  = blockIdx.x >> 1;
    int half = blockIdx.x & 1;
    int r0 = bin << 9;
    int r1 = r0 + 512; if (r1 > N) r1 = N;
    if (r0 >= N) return;
    int beg = rp[r0], end = rp[r1];
    int mid = beg + ((end - beg + 1) >> 1);
    int lo = half ? mid : beg;
    int hi = half ? end : mid;
    for (int i = lo + threadIdx.x; i < hi; i += 256) {
        long long rec = stage[i];
        int d = r0 + soff[i];
        int p = rp[d] + atomicAdd(&cur[d], 1);
        pack[p] = rec;
    }
}

// ---------------- combined gather (width 128): out[row] += sum_i w_i * hc[src'_i] ----------------
__global__ __launch_bounds__(256)
void gather_c128(const _Float16* __restrict__ hc, const int* __restrict__ rp,
                 const long long* __restrict__ pack, float* __restrict__ out, int N)
{
    int row = blockIdx.x * 8 + (threadIdx.x >> 5);
    if (row >= N) return;
    int lane = threadIdx.x & 31;
    int beg = rp[row], end = rp[row + 1];
    float a0 = 0.f, a1 = 0.f, a2 = 0.f, a3 = 0.f;
    int i = beg;
    for (; i + 2 <= end; i += 2) {
        long long q0 = pack[i], q1 = pack[i + 1];
        int   sa = (int)(unsigned)q0,          sb = (int)(unsigned)q1;
        float wa = __int_as_float((int)(q0 >> 32)), wb = __int_as_float((int)(q1 >> 32));
        f16x4 va = *(const f16x4*)(hc + (size_t)sa * 128 + lane * 4);
        f16x4 vb = *(const f16x4*)(hc + (size_t)sb * 128 + lane * 4);
        a0 = fmaf(wa, (float)va[0], a0); a1 = fmaf(wa, (float)va[1], a1);
        a2 = fmaf(wa, (float)va[2], a2); a3 = fmaf(wa, (float)va[3], a3);
        a0 = fmaf(wb, (float)vb[0], a0); a1 = fmaf(wb, (float)vb[1], a1);
        a2 = fmaf(wb, (float)vb[2], a2); a3 = fmaf(wb, (float)vb[3], a3);
    }
    if (i < end) {
        long long q0 = pack[i];
        int   sa = (int)(unsigned)q0;
        float wa = __int_as_float((int)(q0 >> 32));
        f16x4 va = *(const f16x4*)(hc + (size_t)sa * 128 + lane * 4);
        a0 = fmaf(wa, (float)va[0], a0); a1 = fmaf(wa, (float)va[1], a1);
        a2 = fmaf(wa, (float)va[2], a2); a3 = fmaf(wa, (float)va[3], a3);
    }
    float* o = out + (size_t)row * 128 + lane * 4;
    float4 c = *(float4*)o;
    c.x += a0; c.y += a1; c.z += a2; c.w += a3;
    *(float4*)o = c;
}

// ---------------- final: gather (width 40) + log_softmax fused, writes d_out ----------------
__global__ __launch_bounds__(256)
void gather_ls40(const _Float16* __restrict__ hc, const int* __restrict__ rp,
                 const long long* __restrict__ pack, const float* __restrict__ xlin,
                 float* __restrict__ out, int N)
{
    int row = blockIdx.x * 16 + (threadIdx.x >> 4);
    int lane = threadIdx.x & 15;
    if (row >= N) return;                      // whole 16-lane group exits together
    bool act = (lane < 10);

    float v0 = -INFINITY, v1 = -INFINITY, v2 = -INFINITY, v3 = -INFINITY;
    if (act) {
        float a0 = 0.f, a1 = 0.f, a2 = 0.f, a3 = 0.f;
        int beg = rp[row], end = rp[row + 1];
        int i = beg;
        for (; i + 2 <= end; i += 2) {
            long long q0 = pack[i], q1 = pack[i + 1];
            int   sa = (int)(unsigned)q0,          sb = (int)(unsigned)q1;
            float wa = __int_as_float((int)(q0 >> 32)), wb = __int_as_float((int)(q1 >> 32));
            f16x4 va = *(const f16x4*)(hc + (size_t)sa * 40 + lane * 4);
            f16x4 vb = *(const f16x4*)(hc + (size_t)sb * 40 + lane * 4);
            a0 = fmaf(wa, (float)va[0], a0); a1 = fmaf(wa, (float)va[1], a1);
            a2 = fmaf(wa, (float)va[2], a2); a3 = fmaf(wa, (float)va[3], a3);
            a0 = fmaf(wb, (float)vb[0], a0); a1 = fmaf(wb, (float)vb[1], a1);
            a2 = fmaf(wb, (float)vb[2], a2); a3 = fmaf(wb, (float)vb[3], a3);
        }
        if (i < end) {
            long long q0 = pack[i];
            int   sa = (int)(unsigned)q0;
            float wa = __int_as_float((int)(q0 >> 32));
            f16x4 va = *(const f16x4*)(hc + (size_t)sa * 40 + lane * 4);
            a0 = fmaf(wa, (float)va[0], a0); a1 = fmaf(wa, (float)va[1], a1);
            a2 = fmaf(wa, (float)va[2], a2); a3 = fmaf(wa, (float)va[3], a3);
        }
        float4 c = *(const float4*)(xlin + (size_t)row * 40 + lane * 4);
        v0 = c.x + a0; v1 = c.y + a1; v2 = c.z + a2; v3 = c.w + a3;
    }

    float m = fmaxf(fmaxf(v0, v1), fmaxf(v2, v3));
    #pragma unroll
    for (int off = 8; off; off >>= 1) m = fmaxf(m, __shfl_xor(m, off, 16));
    float s = 0.f;
    if (act) s = expf(v0 - m) + expf(v1 - m) + expf(v2 - m) + expf(v3 - m);
    #pragma unroll
    for (int off = 8; off; off >>= 1) s += __shfl_xor(s, off, 16);
    float ls = m + logf(s);

    if (act) {
        float* o = out + (size_t)row * 40 + lane * 4;
        o[0] = v0 - ls; o[1] = v1 - ls; o[2] = v2 - ls; o[3] = v3 - ls;
    }
}

// ---------------- launch ----------------
extern "C" void kernel_launch(void* const* d_in, const int* in_sizes, int n_in,
                              void* d_out, int out_size, void* d_ws, size_t ws_size,
                              hipStream_t stream)
{
    const float* x    = (const float*)d_in[0];
    const int*   ei1  = (const int*)  d_in[1];
    const float* ew1  = (const float*)d_in[2];
    const int*   ei2  = (const int*)  d_in[3];
    const float* ew2  = (const float*)d_in[4];

    const float* W_ln1 = (const float*)d_in[5];   const float* b_ln1 = (const float*)d_in[6];
    const float* W_c11 = (const float*)d_in[7];   const float* b_c11 = (const float*)d_in[8];
    const float* W_c21 = (const float*)d_in[9];   const float* b_c21 = (const float*)d_in[10];
    const float* W_ln2 = (const float*)d_in[11];  const float* b_ln2 = (const float*)d_in[12];
    const float* W_c12 = (const float*)d_in[13];  const float* b_c12 = (const float*)d_in[14];
    const float* W_c22 = (const float*)d_in[15];  const float* b_c22 = (const float*)d_in[16];
    const float* W_ln3 = (const float*)d_in[17];  const float* b_ln3 = (const float*)d_in[18];
    const float* W_c13 = (const float*)d_in[19];  const float* b_c13 = (const float*)d_in[20];
    const float* W_c23 = (const float*)d_in[21];  const float* b_c23 = (const float*)d_in[22];

    const int N = in_sizes[0] / 128;   // 50000
    const int E = in_sizes[2];         // 600000
    const int nbins = (N + 511) >> 9;  // 98

    // ---- workspace layout ----
    auto align_up = [](size_t v) { return (v + 255) & ~(size_t)255; };
    char* base = (char*)d_ws;
    size_t off = 0;
    auto take = [&](size_t bytes) { char* p = base + off; off += align_up(bytes); return p; };

    float*     xA   = (float*)    take((size_t)N * 128 * 4);
    float*     xB   = (float*)    take((size_t)N * 128 * 4);
    _Float16*  hc   = (_Float16*) take((size_t)2 * N * 128 * 2);   // combined [2N][128]; layer3 aliases [2N][40]

    _Float16* Wt1 = (_Float16*)take((size_t)3 * 2 * 128 * 128 * 2);
    _Float16* Wt2 = (_Float16*)take((size_t)3 * 2 * 128 * 128 * 2);
    _Float16* Wt3 = (_Float16*)take((size_t)3 * 2 * 64 * 128 * 2);

    int*       cnt  = (int*)      take((size_t)N * 4);
    int*       rp   = (int*)      take((size_t)(N + 1) * 4);
    long long* pack = (long long*)take((size_t)2 * E * 8);
    int*       bs   = (int*)      take(256 * 4);
    int*       bincur = (int*)    take(MAXB * 4);

    // staging aliases hc (dead until first gemm3)
    long long*      stage = (long long*)hc;
    unsigned short* soff  = (unsigned short*)((char*)hc + (size_t)2 * E * 8);

    dim3 blk(256);
    const int gN   = (N + 255) / 256;
    const int gN1  = (N + 1 + 255) / 256;
    const int gE2  = (2 * E + 255) / 256;
    const int gBF  = (2 * E + EPB - 1) / EPB;
    const int gRT  = (N + 63) / 64;            // 782 row tiles
    dim3 gg3_128(gRT, 3, 2);
    dim3 gg3_40(gRT, 3, 1);
    dim3 gg128((N + 7) / 8);
    dim3 gg40((N + 15) / 16);

    // ---- W preprocessing ----
    wsplit3<<<dim3((128 * 128 + 255) / 256, 3), blk, 0, stream>>>(W_ln1, W_c11, W_c21, Wt1, 128, 128);
    wsplit3<<<dim3((128 * 128 + 255) / 256, 3), blk, 0, stream>>>(W_ln2, W_c12, W_c22, Wt2, 128, 128);
    wsplit3<<<dim3((64 * 128 + 255) / 256, 3), blk, 0, stream>>>(W_ln3, W_c13, W_c23, Wt3, 40, 64);

    // ---- build combined CSR ----
    zero_i32<<<gN, blk, 0, stream>>>(cnt, N);
    hist_c<<<gE2, blk, 0, stream>>>(ei1, ei2, E, cnt);
    scan_phase1<<<gN1, blk, 0, stream>>>(cnt, N, bs, N + 1);
    scan_phase2<<<1, blk, 0, stream>>>(bs, gN1);
    scan_phase3<<<gN1, blk, 0, stream>>>(cnt, N, bs, rp, N + 1);
    init_bincur<<<1, blk, 0, stream>>>(rp, N, nbins, bincur);
    binfill<<<gBF, blk, 0, stream>>>(ei1, ew1, ei2, ew2, E, N, nbins, bincur, stage, soff);
    binplace<<<nbins * 2, blk, 0, stream>>>(stage, soff, rp, N, cnt, pack);

    // ---- Block 1: x -> xA ----
    gemm3<128><<<gg3_128, blk, 0, stream>>>(x, Wt1, b_ln1, b_c11, b_c21, xA, hc, hc + (size_t)N * 128, 128, N);
    gather_c128<<<gg128, blk, 0, stream>>>(hc, rp, pack, xA, N);

    // ---- Block 2: xA -> xB ----
    gemm3<128><<<gg3_128, blk, 0, stream>>>(xA, Wt2, b_ln2, b_c12, b_c22, xB, hc, hc + (size_t)N * 128, 128, N);
    gather_c128<<<gg128, blk, 0, stream>>>(hc, rp, pack, xB, N);

    // ---- Block 3: xB -> xA (width 40), then fused gather+log_softmax -> d_out ----
    gemm3<64><<<gg3_40, blk, 0, stream>>>(xB, Wt3, b_ln3, b_c13, b_c23, xA, hc, hc + (size_t)N * 40, 40, N);
    gather_ls40<<<gg40, blk, 0, stream>>>(hc, rp, pack, xA, (float*)d_out, N);
}